// Round 1
// baseline (29225.766 us; speedup 1.0000x reference)
//
#include <hip/hip_runtime.h>

#define BB 8
#define SS 1024
#define LL 12
#define DD 768
#define HH 12
#define FF 3072
#define VV 21128
#define DH 64
#define CLEN 960
#define NROWS (BB * CLEN)        // 7680 classifier rows
#define TOKS (BB * SS)           // 8192 token rows
#define CHUNK 2048               // classifier column chunk

typedef __attribute__((ext_vector_type(8))) short bh8;
typedef __attribute__((ext_vector_type(4))) float f32x4;

__device__ __forceinline__ float bf2f(unsigned short u) {
    union { unsigned int i; float f; } c; c.i = ((unsigned int)u) << 16; return c.f;
}
__device__ __forceinline__ unsigned short f2bf(float f) {
    union { float f; unsigned int i; } c; c.f = f;
    unsigned int r = c.i + 0x7fffu + ((c.i >> 16) & 1u);
    return (unsigned short)(r >> 16);
}

// 256-thread block sum; red must be shared float[4]
__device__ __forceinline__ float bsum256(float v, float* red) {
#pragma unroll
    for (int o = 32; o; o >>= 1) v += __shfl_down(v, o);
    if ((threadIdx.x & 63) == 0) red[threadIdx.x >> 6] = v;
    __syncthreads();
    float r = red[0] + red[1] + red[2] + red[3];
    __syncthreads();
    return r;
}

// ---------------- transpose fp32 [R,C] -> bf16 [C,R] ----------------
__global__ void transpose_f32_bf16(const float* __restrict__ in, unsigned short* __restrict__ out,
                                   int R, int C) {
    __shared__ float tile[32][33];
    int c0 = blockIdx.x << 5, r0 = blockIdx.y << 5;
    int tx = threadIdx.x, ty = threadIdx.y;
    for (int i = ty; i < 32; i += 8) {
        int r = r0 + i, c = c0 + tx;
        if (r < R && c < C) tile[i][tx] = in[(size_t)r * C + c];
    }
    __syncthreads();
    for (int i = ty; i < 32; i += 8) {
        int oc = c0 + i, orr = r0 + tx;
        if (oc < C && orr < R) out[(size_t)oc * R + orr] = f2bf(tile[tx][i]);
    }
}

// ---------------- embedding + LN ----------------
__global__ __launch_bounds__(256) void embed_ln(const int* __restrict__ x, const float* __restrict__ we,
                                                const float* __restrict__ pe, const float* __restrict__ te,
                                                const float* __restrict__ g, const float* __restrict__ be,
                                                float* __restrict__ hf, unsigned short* __restrict__ hb) {
    int row = blockIdx.x;            // b*S + s
    int s = row & (SS - 1);
    int tok = x[row];
    int tid = threadIdx.x;
    __shared__ float red[4];
    float v[3];
#pragma unroll
    for (int i = 0; i < 3; i++) {
        int c = tid + i * 256;
        v[i] = we[(size_t)tok * DD + c] + pe[(size_t)s * DD + c] + te[c];
    }
    float mean = bsum256(v[0] + v[1] + v[2], red) * (1.f / DD);
    float d0 = v[0] - mean, d1 = v[1] - mean, d2 = v[2] - mean;
    float var = bsum256(d0 * d0 + d1 * d1 + d2 * d2, red) * (1.f / DD);
    float inv = rsqrtf(var + 1e-12f);
    size_t base = (size_t)row * DD;
#pragma unroll
    for (int i = 0; i < 3; i++) {
        int c = tid + i * 256;
        float o = (v[i] - mean) * inv * g[c] + be[c];
        hf[base + c] = o;
        hb[base + c] = f2bf(o);
    }
}

// ---------------- residual add + LN (dual output) ----------------
__global__ __launch_bounds__(256) void add_ln(const float* __restrict__ res, const float* __restrict__ t,
                                              const float* __restrict__ g, const float* __restrict__ be,
                                              float* __restrict__ outf, unsigned short* __restrict__ outb) {
    int row = blockIdx.x;
    int tid = threadIdx.x;
    __shared__ float red[4];
    size_t base = (size_t)row * DD;
    float v[3];
#pragma unroll
    for (int i = 0; i < 3; i++) {
        int c = tid + i * 256;
        v[i] = res[base + c] + t[base + c];
    }
    float mean = bsum256(v[0] + v[1] + v[2], red) * (1.f / DD);
    float d0 = v[0] - mean, d1 = v[1] - mean, d2 = v[2] - mean;
    float var = bsum256(d0 * d0 + d1 * d1 + d2 * d2, red) * (1.f / DD);
    float inv = rsqrtf(var + 1e-12f);
#pragma unroll
    for (int i = 0; i < 3; i++) {
        int c = tid + i * 256;
        float o = (v[i] - mean) * inv * g[c] + be[c];
        outf[base + c] = o;
        outb[base + c] = f2bf(o);
    }
}

// ---------------- MFMA GEMM: C[M,N] = A[M,K](bf16) * BT[N,K](bf16)^T + bias ----------------
// MODE 0: fp32 out; 1: bf16 out; 2: bf16 out with exact GELU
template <int MODE>
__global__ __launch_bounds__(256) void gemm_bt(const unsigned short* __restrict__ A,
                                               const unsigned short* __restrict__ BT,
                                               const float* __restrict__ bias, void* __restrict__ Cp,
                                               int M, int N, int K) {
    __shared__ __align__(16) unsigned short As[64][40];
    __shared__ __align__(16) unsigned short Bs[64][40];
    int tid = threadIdx.x;
    int m0 = blockIdx.y << 6, n0 = blockIdx.x << 6;
    int lane = tid & 63, wave = tid >> 6;
    int wr = wave >> 1, wc = wave & 1;
    f32x4 acc[2][2] = {};
    int lr = tid >> 2, lk = (tid & 3) << 3;
    int fr = lane & 15, g8 = (lane >> 4) << 3;
    const bool bok = (n0 + lr) < N;
    const size_t arow = (size_t)(m0 + lr) * K;
    const size_t brow = (size_t)(n0 + lr) * K;
    for (int k0 = 0; k0 < K; k0 += 32) {
        *(bh8*)&As[lr][lk] = *(const bh8*)&A[arow + k0 + lk];
        bh8 bv = {};
        if (bok) bv = *(const bh8*)&BT[brow + k0 + lk];
        *(bh8*)&Bs[lr][lk] = bv;
        __syncthreads();
        bh8 a0 = *(const bh8*)&As[wr * 32 + fr][g8];
        bh8 a1 = *(const bh8*)&As[wr * 32 + 16 + fr][g8];
        bh8 b0 = *(const bh8*)&Bs[wc * 32 + fr][g8];
        bh8 b1 = *(const bh8*)&Bs[wc * 32 + 16 + fr][g8];
        acc[0][0] = __builtin_amdgcn_mfma_f32_16x16x32_bf16(a0, b0, acc[0][0], 0, 0, 0);
        acc[0][1] = __builtin_amdgcn_mfma_f32_16x16x32_bf16(a0, b1, acc[0][1], 0, 0, 0);
        acc[1][0] = __builtin_amdgcn_mfma_f32_16x16x32_bf16(a1, b0, acc[1][0], 0, 0, 0);
        acc[1][1] = __builtin_amdgcn_mfma_f32_16x16x32_bf16(a1, b1, acc[1][1], 0, 0, 0);
        __syncthreads();
    }
    float* Cf = (float*)Cp;
    unsigned short* Cb = (unsigned short*)Cp;
#pragma unroll
    for (int m = 0; m < 2; m++) {
#pragma unroll
        for (int n = 0; n < 2; n++) {
            int col = n0 + wc * 32 + n * 16 + fr;
            if (col < N) {
                float bb = bias[col];
#pragma unroll
                for (int r = 0; r < 4; r++) {
                    int row = m0 + wr * 32 + m * 16 + ((lane >> 4) << 2) + r;
                    float v = acc[m][n][r] + bb;
                    if (MODE == 2) v = 0.5f * v * (1.0f + erff(v * 0.70710678118f));
                    if (MODE == 0) Cf[(size_t)row * N + col] = v;
                    else Cb[(size_t)row * N + col] = f2bf(v);
                }
            }
        }
    }
}

// ---------------- attention: one block per (q, h, b); prefix mask => keys [0, max(64,q+1)) ----------------
__global__ __launch_bounds__(256) void attn(const unsigned short* __restrict__ qb,
                                            const unsigned short* __restrict__ kb,
                                            const unsigned short* __restrict__ vb,
                                            unsigned short* __restrict__ ctxb) {
    int qi = blockIdx.x, hh = blockIdx.y, b = blockIdx.z;
    int tid = threadIdx.x;
    int cnt = qi < 64 ? 64 : qi + 1;
    __shared__ float qs[DH];
    __shared__ float sc[SS];
    __shared__ float red[4];
    __shared__ float cacc[4][DH];
    const unsigned short* qr = qb + (((size_t)b * SS + qi) * HH + hh) * DH;
    if (tid < DH) qs[tid] = bf2f(qr[tid]);
    __syncthreads();
    float lmax = -3e38f;
    for (int kk = tid; kk < cnt; kk += 256) {
        const unsigned short* kr = kb + (((size_t)b * SS + kk) * HH + hh) * DH;
        float s = 0.f;
#pragma unroll
        for (int c = 0; c < 8; c++) {
            bh8 kv = *(const bh8*)(kr + c * 8);
#pragma unroll
            for (int u = 0; u < 8; u++) s += qs[c * 8 + u] * bf2f((unsigned short)kv[u]);
        }
        s *= 0.125f;
        sc[kk] = s;
        lmax = fmaxf(lmax, s);
    }
#pragma unroll
    for (int o = 32; o; o >>= 1) lmax = fmaxf(lmax, __shfl_down(lmax, o));
    if ((tid & 63) == 0) red[tid >> 6] = lmax;
    __syncthreads();
    float gmax = fmaxf(fmaxf(red[0], red[1]), fmaxf(red[2], red[3]));
    __syncthreads();
    float lsum = 0.f;
    for (int kk = tid; kk < cnt; kk += 256) {
        float e = __expf(sc[kk] - gmax);
        sc[kk] = e;
        lsum += e;
    }
#pragma unroll
    for (int o = 32; o; o >>= 1) lsum += __shfl_down(lsum, o);
    if ((tid & 63) == 0) red[tid >> 6] = lsum;
    __syncthreads();
    float gsum = red[0] + red[1] + red[2] + red[3];
    int d = tid & 63, part = tid >> 6;
    float acc = 0.f;
    for (int kk = part; kk < cnt; kk += 4)
        acc += sc[kk] * bf2f(vb[(((size_t)b * SS + kk) * HH + hh) * DH + d]);
    cacc[part][d] = acc;
    __syncthreads();
    if (tid < DH) {
        float r = (cacc[0][d] + cacc[1][d] + cacc[2][d] + cacc[3][d]) / gsum;
        ctxb[(((size_t)b * SS + qi) * HH + hh) * DH + d] = f2bf(r);
    }
}

// ---------------- gather classifier rows (s in [64,1024)) into compact [7680,768] bf16 ----------------
__global__ void gather_rows(const unsigned short* __restrict__ hb, unsigned short* __restrict__ hc) {
    int idx = blockIdx.x * 256 + threadIdx.x;   // chunk of 8
    if (idx >= NROWS * (DD / 8)) return;
    int g = idx / (DD / 8), c8 = (idx % (DD / 8)) * 8;
    int b = g / CLEN, cc = g % CLEN;
    *(bh8*)&hc[(size_t)g * DD + c8] = *(const bh8*)&hb[((size_t)(b * SS + 64 + cc)) * DD + c8];
}

// ---------------- classifier logsumexp state ----------------
__global__ void init_state(float* stM, float* stS, float* stT) {
    int i = blockIdx.x * 256 + threadIdx.x;
    if (i < NROWS) { stM[i] = -3e38f; stS[i] = 0.f; stT[i] = 0.f; }
}

__global__ __launch_bounds__(256) void lse_merge(const unsigned short* __restrict__ lchunk,
                                                 const int* __restrict__ y,
                                                 float* __restrict__ stM, float* __restrict__ stS,
                                                 float* __restrict__ stT, int c0, int cn) {
    int row = blockIdx.x, tid = threadIdx.x;
    int yv = y[row];
    int tloc = yv - c0;
    const unsigned short* lr = lchunk + (size_t)row * cn;
    float mx = -3e38f, sm = 0.f, tl = 0.f;
    for (int c = tid * 8; c < cn; c += 2048) {
        bh8 lv = *(const bh8*)&lr[c];
#pragma unroll
        for (int u = 0; u < 8; u++) {
            float d = bf2f((unsigned short)lv[u]);
            float m2 = fmaxf(mx, d);
            sm = sm * __expf(mx - m2) + __expf(d - m2);
            mx = m2;
            if (c + u == tloc) tl = d;
        }
    }
    __shared__ float red[4];
    float m = mx;
#pragma unroll
    for (int o = 32; o; o >>= 1) m = fmaxf(m, __shfl_down(m, o));
    if ((tid & 63) == 0) red[tid >> 6] = m;
    __syncthreads();
    float gmax = fmaxf(fmaxf(red[0], red[1]), fmaxf(red[2], red[3]));
    __syncthreads();
    float s = sm * __expf(mx - gmax);
#pragma unroll
    for (int o = 32; o; o >>= 1) s += __shfl_down(s, o);
    if ((tid & 63) == 0) red[tid >> 6] = s;
    __syncthreads();
    float gsum = red[0] + red[1] + red[2] + red[3];
    __syncthreads();
    float t = tl;
#pragma unroll
    for (int o = 32; o; o >>= 1) t += __shfl_down(t, o);
    if ((tid & 63) == 0) red[tid >> 6] = t;
    __syncthreads();
    float gt = red[0] + red[1] + red[2] + red[3];
    if (tid == 0) {
        float M0 = stM[row], S0 = stS[row];
        float M = fmaxf(M0, gmax);
        float S = S0 * __expf(M0 - M) + gsum * __expf(gmax - M);
        stM[row] = M;
        stS[row] = S;
        if (tloc >= 0 && tloc < cn) stT[row] = gt;
    }
}

__global__ __launch_bounds__(256) void final_reduce(const float* __restrict__ stM, const float* __restrict__ stS,
                                                    const float* __restrict__ stT, const int* __restrict__ y,
                                                    float* __restrict__ out) {
    int tid = threadIdx.x;
    float s = 0.f, c = 0.f;
    for (int i = tid; i < NROWS; i += 256) {
        if (y[i] != -100) {
            s += stM[i] + logf(stS[i]) - stT[i];
            c += 1.f;
        }
    }
    __shared__ float red[4];
    float gs = bsum256(s, red);
    float gc = bsum256(c, red);
    if (tid == 0) out[0] = gs / fmaxf(gc, 1.f);
}

// ---------------- launcher ----------------
extern "C" void kernel_launch(void* const* d_in, const int* in_sizes, int n_in,
                              void* d_out, int out_size, void* d_ws, size_t ws_size,
                              hipStream_t stream) {
    const int* x = (const int*)d_in[0];
    const int* y = (const int*)d_in[1];
    const float* we = (const float*)d_in[2];
    const float* pe = (const float*)d_in[3];
    const float* te = (const float*)d_in[4];
    const float* eg = (const float*)d_in[5];
    const float* eb = (const float*)d_in[6];
    const float* Wq = (const float*)d_in[7];
    const float* bq = (const float*)d_in[8];
    const float* Wk = (const float*)d_in[9];
    const float* bk = (const float*)d_in[10];
    const float* Wv = (const float*)d_in[11];
    const float* bv = (const float*)d_in[12];
    const float* Wo = (const float*)d_in[13];
    const float* bo = (const float*)d_in[14];
    const float* g1 = (const float*)d_in[15];
    const float* b1n = (const float*)d_in[16];
    const float* W1 = (const float*)d_in[17];
    const float* b1 = (const float*)d_in[18];
    const float* W2 = (const float*)d_in[19];
    const float* b2 = (const float*)d_in[20];
    const float* g2 = (const float*)d_in[21];
    const float* b2n = (const float*)d_in[22];
    const float* clsW = (const float*)d_in[23];
    const float* clsb = (const float*)d_in[24];
    float* out = (float*)d_out;

    char* ws = (char*)d_ws;
    size_t off = 0;
    auto alloc = [&](size_t n) {
        void* p = ws + off;
        off += n;
        off = (off + 255) & ~(size_t)255;
        return p;
    };
    float* h   = (float*)alloc((size_t)TOKS * DD * 4);
    float* h1  = (float*)alloc((size_t)TOKS * DD * 4);
    float* tmp = (float*)alloc((size_t)TOKS * DD * 4);
    unsigned short* hb   = (unsigned short*)alloc((size_t)TOKS * DD * 2);
    unsigned short* h1b  = (unsigned short*)alloc((size_t)TOKS * DD * 2);
    unsigned short* qbuf = (unsigned short*)alloc((size_t)TOKS * DD * 2);
    unsigned short* kbuf = (unsigned short*)alloc((size_t)TOKS * DD * 2);
    unsigned short* vbuf = (unsigned short*)alloc((size_t)TOKS * DD * 2);
    unsigned short* ctxb = (unsigned short*)alloc((size_t)TOKS * DD * 2);
    unsigned short* ffnb = (unsigned short*)alloc((size_t)TOKS * FF * 2);
    unsigned short* wqT = (unsigned short*)alloc((size_t)DD * DD * 2);
    unsigned short* wkT = (unsigned short*)alloc((size_t)DD * DD * 2);
    unsigned short* wvT = (unsigned short*)alloc((size_t)DD * DD * 2);
    unsigned short* woT = (unsigned short*)alloc((size_t)DD * DD * 2);
    unsigned short* w1T = (unsigned short*)alloc((size_t)DD * FF * 2);
    unsigned short* w2T = (unsigned short*)alloc((size_t)DD * FF * 2);
    unsigned short* clsT = (unsigned short*)alloc((size_t)VV * DD * 2);
    unsigned short* hc = (unsigned short*)alloc((size_t)NROWS * DD * 2);
    unsigned short* lchunk = (unsigned short*)alloc((size_t)NROWS * CHUNK * 2);
    float* stM = (float*)alloc(NROWS * 4);
    float* stS = (float*)alloc(NROWS * 4);
    float* stT = (float*)alloc(NROWS * 4);

    dim3 tb(32, 8);
    // classifier weight transpose: clsW [768, 21128] -> clsT [21128, 768]
    transpose_f32_bf16<<<dim3((VV + 31) / 32, DD / 32), tb, 0, stream>>>(clsW, clsT, DD, VV);
    // embedding
    embed_ln<<<TOKS, 256, 0, stream>>>(x, we, pe, te, eg, eb, h, hb);

    for (int l = 0; l < LL; l++) {
        const float* Wq_l = Wq + (size_t)l * DD * DD;
        const float* Wk_l = Wk + (size_t)l * DD * DD;
        const float* Wv_l = Wv + (size_t)l * DD * DD;
        const float* Wo_l = Wo + (size_t)l * DD * DD;
        const float* W1_l = W1 + (size_t)l * DD * FF;
        const float* W2_l = W2 + (size_t)l * FF * DD;
        transpose_f32_bf16<<<dim3(DD / 32, DD / 32), tb, 0, stream>>>(Wq_l, wqT, DD, DD);
        transpose_f32_bf16<<<dim3(DD / 32, DD / 32), tb, 0, stream>>>(Wk_l, wkT, DD, DD);
        transpose_f32_bf16<<<dim3(DD / 32, DD / 32), tb, 0, stream>>>(Wv_l, wvT, DD, DD);
        transpose_f32_bf16<<<dim3(DD / 32, DD / 32), tb, 0, stream>>>(Wo_l, woT, DD, DD);
        transpose_f32_bf16<<<dim3(FF / 32, DD / 32), tb, 0, stream>>>(W1_l, w1T, DD, FF);
        transpose_f32_bf16<<<dim3(DD / 32, FF / 32), tb, 0, stream>>>(W2_l, w2T, FF, DD);

        dim3 gqkv(DD / 64, TOKS / 64);
        gemm_bt<1><<<gqkv, 256, 0, stream>>>(hb, wqT, bq + (size_t)l * DD, qbuf, TOKS, DD, DD);
        gemm_bt<1><<<gqkv, 256, 0, stream>>>(hb, wkT, bk + (size_t)l * DD, kbuf, TOKS, DD, DD);
        gemm_bt<1><<<gqkv, 256, 0, stream>>>(hb, wvT, bv + (size_t)l * DD, vbuf, TOKS, DD, DD);

        attn<<<dim3(SS, HH, BB), 256, 0, stream>>>(qbuf, kbuf, vbuf, ctxb);

        gemm_bt<0><<<gqkv, 256, 0, stream>>>(ctxb, woT, bo + (size_t)l * DD, tmp, TOKS, DD, DD);
        add_ln<<<TOKS, 256, 0, stream>>>(h, tmp, g1 + (size_t)l * DD, b1n + (size_t)l * DD, h1, h1b);

        gemm_bt<2><<<dim3(FF / 64, TOKS / 64), 256, 0, stream>>>(h1b, w1T, b1 + (size_t)l * FF, ffnb, TOKS, FF, DD);
        gemm_bt<0><<<gqkv, 256, 0, stream>>>(ffnb, w2T, b2 + (size_t)l * DD, tmp, TOKS, DD, FF);
        add_ln<<<TOKS, 256, 0, stream>>>(h1, tmp, g2 + (size_t)l * DD, b2n + (size_t)l * DD, h, hb);
    }

    // classifier
    gather_rows<<<(NROWS * (DD / 8) + 255) / 256, 256, 0, stream>>>(hb, hc);
    init_state<<<(NROWS + 255) / 256, 256, 0, stream>>>(stM, stS, stT);
    for (int c0 = 0; c0 < VV; c0 += CHUNK) {
        int cn = VV - c0 < CHUNK ? VV - c0 : CHUNK;
        dim3 gc((cn + 63) / 64, NROWS / 64);
        gemm_bt<1><<<gc, 256, 0, stream>>>(hc, clsT + (size_t)c0 * DD, clsb + c0, lchunk, NROWS, cn, DD);
        lse_merge<<<NROWS, 256, 0, stream>>>(lchunk, y, stM, stS, stT, c0, cn);
    }
    final_reduce<<<1, 256, 0, stream>>>(stM, stS, stT, y, out);
}

// Round 2
// 6559.150 us; speedup vs baseline: 4.4557x; 4.4557x over previous
//
#include <hip/hip_runtime.h>

#define BB 8
#define SS 1024
#define LL 12
#define DD 768
#define HH 12
#define FF 3072
#define VV 21128
#define DH 64
#define CLEN 960
#define NROWS (BB * CLEN)        // 7680 classifier rows
#define TOKS (BB * SS)           // 8192 token rows
#define CHUNK 2048               // classifier column chunk

typedef __attribute__((ext_vector_type(8))) short bh8;
typedef __attribute__((ext_vector_type(4))) float f32x4;

__device__ __forceinline__ float bf2f(unsigned short u) {
    union { unsigned int i; float f; } c; c.i = ((unsigned int)u) << 16; return c.f;
}
__device__ __forceinline__ unsigned short f2bf(float f) {
    union { float f; unsigned int i; } c; c.f = f;
    unsigned int r = c.i + 0x7fffu + ((c.i >> 16) & 1u);
    return (unsigned short)(r >> 16);
}

// 256-thread block sum; red must be shared float[4]
__device__ __forceinline__ float bsum256(float v, float* red) {
#pragma unroll
    for (int o = 32; o; o >>= 1) v += __shfl_down(v, o);
    if ((threadIdx.x & 63) == 0) red[threadIdx.x >> 6] = v;
    __syncthreads();
    float r = red[0] + red[1] + red[2] + red[3];
    __syncthreads();
    return r;
}

// ---------------- transpose fp32 [R,C] -> bf16 [C,R] ----------------
__global__ void transpose_f32_bf16(const float* __restrict__ in, unsigned short* __restrict__ out,
                                   int R, int C) {
    __shared__ float tile[32][33];
    int c0 = blockIdx.x << 5, r0 = blockIdx.y << 5;
    int tx = threadIdx.x, ty = threadIdx.y;
    for (int i = ty; i < 32; i += 8) {
        int r = r0 + i, c = c0 + tx;
        if (r < R && c < C) tile[i][tx] = in[(size_t)r * C + c];
    }
    __syncthreads();
    for (int i = ty; i < 32; i += 8) {
        int oc = c0 + i, orr = r0 + tx;
        if (oc < C && orr < R) out[(size_t)oc * R + orr] = f2bf(tile[tx][i]);
    }
}

// ---------------- embedding + LN ----------------
__global__ __launch_bounds__(256) void embed_ln(const int* __restrict__ x, const float* __restrict__ we,
                                                const float* __restrict__ pe, const float* __restrict__ te,
                                                const float* __restrict__ g, const float* __restrict__ be,
                                                float* __restrict__ hf, unsigned short* __restrict__ hb) {
    int row = blockIdx.x;            // b*S + s
    int s = row & (SS - 1);
    int tok = x[row];
    int tid = threadIdx.x;
    __shared__ float red[4];
    float v[3];
#pragma unroll
    for (int i = 0; i < 3; i++) {
        int c = tid + i * 256;
        v[i] = we[(size_t)tok * DD + c] + pe[(size_t)s * DD + c] + te[c];
    }
    float mean = bsum256(v[0] + v[1] + v[2], red) * (1.f / DD);
    float d0 = v[0] - mean, d1 = v[1] - mean, d2 = v[2] - mean;
    float var = bsum256(d0 * d0 + d1 * d1 + d2 * d2, red) * (1.f / DD);
    float inv = rsqrtf(var + 1e-12f);
    size_t base = (size_t)row * DD;
#pragma unroll
    for (int i = 0; i < 3; i++) {
        int c = tid + i * 256;
        float o = (v[i] - mean) * inv * g[c] + be[c];
        hf[base + c] = o;
        hb[base + c] = f2bf(o);
    }
}

// ---------------- residual add + LN (dual output) ----------------
__global__ __launch_bounds__(256) void add_ln(const float* __restrict__ res, const float* __restrict__ t,
                                              const float* __restrict__ g, const float* __restrict__ be,
                                              float* __restrict__ outf, unsigned short* __restrict__ outb) {
    int row = blockIdx.x;
    int tid = threadIdx.x;
    __shared__ float red[4];
    size_t base = (size_t)row * DD;
    float v[3];
#pragma unroll
    for (int i = 0; i < 3; i++) {
        int c = tid + i * 256;
        v[i] = res[base + c] + t[base + c];
    }
    float mean = bsum256(v[0] + v[1] + v[2], red) * (1.f / DD);
    float d0 = v[0] - mean, d1 = v[1] - mean, d2 = v[2] - mean;
    float var = bsum256(d0 * d0 + d1 * d1 + d2 * d2, red) * (1.f / DD);
    float inv = rsqrtf(var + 1e-12f);
#pragma unroll
    for (int i = 0; i < 3; i++) {
        int c = tid + i * 256;
        float o = (v[i] - mean) * inv * g[c] + be[c];
        outf[base + c] = o;
        outb[base + c] = f2bf(o);
    }
}

// ---------------- MFMA GEMM: C[M,N] = A[M,K](bf16) * BT[N,K](bf16)^T + bias ----------------
// MODE 0: fp32 out; 1: bf16 out; 2: bf16 out with exact GELU
template <int MODE>
__global__ __launch_bounds__(256) void gemm_bt(const unsigned short* __restrict__ A,
                                               const unsigned short* __restrict__ BT,
                                               const float* __restrict__ bias, void* __restrict__ Cp,
                                               int M, int N, int K) {
    __shared__ __align__(16) unsigned short As[64][40];
    __shared__ __align__(16) unsigned short Bs[64][40];
    int tid = threadIdx.x;
    int m0 = blockIdx.y << 6, n0 = blockIdx.x << 6;
    int lane = tid & 63, wave = tid >> 6;
    int wr = wave >> 1, wc = wave & 1;
    f32x4 acc[2][2] = {};
    int lr = tid >> 2, lk = (tid & 3) << 3;
    int fr = lane & 15, g8 = (lane >> 4) << 3;
    const bool bok = (n0 + lr) < N;
    const size_t arow = (size_t)(m0 + lr) * K;
    const size_t brow = (size_t)(n0 + lr) * K;
    for (int k0 = 0; k0 < K; k0 += 32) {
        *(bh8*)&As[lr][lk] = *(const bh8*)&A[arow + k0 + lk];
        bh8 bv = {};
        if (bok) bv = *(const bh8*)&BT[brow + k0 + lk];
        *(bh8*)&Bs[lr][lk] = bv;
        __syncthreads();
        bh8 a0 = *(const bh8*)&As[wr * 32 + fr][g8];
        bh8 a1 = *(const bh8*)&As[wr * 32 + 16 + fr][g8];
        bh8 b0 = *(const bh8*)&Bs[wc * 32 + fr][g8];
        bh8 b1 = *(const bh8*)&Bs[wc * 32 + 16 + fr][g8];
        acc[0][0] = __builtin_amdgcn_mfma_f32_16x16x32_bf16(a0, b0, acc[0][0], 0, 0, 0);
        acc[0][1] = __builtin_amdgcn_mfma_f32_16x16x32_bf16(a0, b1, acc[0][1], 0, 0, 0);
        acc[1][0] = __builtin_amdgcn_mfma_f32_16x16x32_bf16(a1, b0, acc[1][0], 0, 0, 0);
        acc[1][1] = __builtin_amdgcn_mfma_f32_16x16x32_bf16(a1, b1, acc[1][1], 0, 0, 0);
        __syncthreads();
    }
    float* Cf = (float*)Cp;
    unsigned short* Cb = (unsigned short*)Cp;
#pragma unroll
    for (int m = 0; m < 2; m++) {
#pragma unroll
        for (int n = 0; n < 2; n++) {
            int col = n0 + wc * 32 + n * 16 + fr;
            if (col < N) {
                float bb = bias[col];
#pragma unroll
                for (int r = 0; r < 4; r++) {
                    int row = m0 + wr * 32 + m * 16 + ((lane >> 4) << 2) + r;
                    float v = acc[m][n][r] + bb;
                    if (MODE == 2) v = 0.5f * v * (1.0f + erff(v * 0.70710678118f));
                    if (MODE == 0) Cf[(size_t)row * N + col] = v;
                    else Cb[(size_t)row * N + col] = f2bf(v);
                }
            }
        }
    }
}

// ---------------- flash attention: grid (S/64, H, B), 4 waves, 16 Q-rows/wave ----------------
// prefix-LM: Q-tile qt needs K-tiles [0, qt] (qt=0: exactly 1, unmasked; mask only on kt==qt, qt>0)
__global__ __launch_bounds__(256) void flash_attn(const unsigned short* __restrict__ qb,
                                                  const unsigned short* __restrict__ kb,
                                                  const unsigned short* __restrict__ vb,
                                                  unsigned short* __restrict__ ctxb) {
    const int qt = blockIdx.x, h = blockIdx.y, b = blockIdx.z;
    const int tid = threadIdx.x;
    const int lane = tid & 63, w = tid >> 6;
    const int fr = lane & 15, fg = lane >> 4;   // frag row/col-in-16, 16-lane group id
    __shared__ unsigned short Qs[64][72];
    __shared__ unsigned short Ks[64][72];
    __shared__ unsigned short Vt[64][72];       // Vt[d][key]
    __shared__ unsigned short Ps[4][16][72];    // per-wave P [q][key]

    // stage Q tile
    {
        int row = tid >> 2, d0 = (tid & 3) << 4;
        const unsigned short* src = qb + (((size_t)b * SS + qt * 64 + row) * HH + h) * DH + d0;
        *(bh8*)&Qs[row][d0] = *(const bh8*)src;
        *(bh8*)&Qs[row][d0 + 8] = *(const bh8*)(src + 8);
    }

    f32x4 o[4] = {};          // O frags: col d = df*16+fr, row q = qt*64 + w*16 + fg*4 + r
    float m[4], l[4];
#pragma unroll
    for (int r = 0; r < 4; r++) { m[r] = -3e30f; l[r] = 0.f; }

    const int nkt = (qt == 0) ? 1 : qt + 1;
    for (int kt = 0; kt < nkt; kt++) {
        __syncthreads();   // previous tile's LDS reads done before restage
        {
            int row = tid >> 2, d0 = (tid & 3) << 4;
            const unsigned short* ksrc = kb + (((size_t)b * SS + kt * 64 + row) * HH + h) * DH + d0;
            *(bh8*)&Ks[row][d0] = *(const bh8*)ksrc;
            *(bh8*)&Ks[row][d0 + 8] = *(const bh8*)(ksrc + 8);
            const unsigned short* vsrc = vb + (((size_t)b * SS + kt * 64 + row) * HH + h) * DH + d0;
            bh8 v0 = *(const bh8*)vsrc, v1 = *(const bh8*)(vsrc + 8);
#pragma unroll
            for (int j = 0; j < 8; j++) Vt[d0 + j][row] = (unsigned short)v0[j];
#pragma unroll
            for (int j = 0; j < 8; j++) Vt[d0 + 8 + j][row] = (unsigned short)v1[j];
        }
        __syncthreads();

        // QK^T: s[cf] rows = wave's 16 q-rows, cols = kt*64 + cf*16 + fr
        f32x4 s[4] = {};
        bh8 a0 = *(const bh8*)&Qs[w * 16 + fr][fg * 8];
        bh8 a1 = *(const bh8*)&Qs[w * 16 + fr][32 + fg * 8];
#pragma unroll
        for (int cf = 0; cf < 4; cf++) {
            bh8 b0 = *(const bh8*)&Ks[cf * 16 + fr][fg * 8];
            bh8 b1 = *(const bh8*)&Ks[cf * 16 + fr][32 + fg * 8];
            s[cf] = __builtin_amdgcn_mfma_f32_16x16x32_bf16(a0, b0, s[cf], 0, 0, 0);
            s[cf] = __builtin_amdgcn_mfma_f32_16x16x32_bf16(a1, b1, s[cf], 0, 0, 0);
        }
        const bool diag = (qt > 0) && (kt == qt);
#pragma unroll
        for (int cf = 0; cf < 4; cf++) {
#pragma unroll
            for (int r = 0; r < 4; r++) {
                float v = s[cf][r] * 0.125f;
                if (diag) {
                    int key = cf * 16 + fr;              // within tile
                    int qrow = w * 16 + fg * 4 + r;      // within tile (kt==qt)
                    if (key > qrow) v = -1e30f;
                }
                s[cf][r] = v;
            }
        }
        // online softmax: per-row stats (row's 16 cols per frag live across 16-lane group)
        float pm[4], ps[4], sc[4], mn[4];
#pragma unroll
        for (int r = 0; r < 4; r++) {
            float v = fmaxf(fmaxf(s[0][r], s[1][r]), fmaxf(s[2][r], s[3][r]));
#pragma unroll
            for (int off = 1; off < 16; off <<= 1) v = fmaxf(v, __shfl_xor(v, off));
            pm[r] = v;
            mn[r] = fmaxf(m[r], v);
            sc[r] = __expf(m[r] - mn[r]);
            m[r] = mn[r];
        }
#pragma unroll
        for (int cf = 0; cf < 4; cf++) {
#pragma unroll
            for (int r = 0; r < 4; r++) s[cf][r] = __expf(s[cf][r] - mn[r]);
        }
#pragma unroll
        for (int r = 0; r < 4; r++) {
            float v = s[0][r] + s[1][r] + s[2][r] + s[3][r];
#pragma unroll
            for (int off = 1; off < 16; off <<= 1) v += __shfl_xor(v, off);
            ps[r] = v;
            l[r] = l[r] * sc[r] + ps[r];
        }
#pragma unroll
        for (int df = 0; df < 4; df++) {
#pragma unroll
            for (int r = 0; r < 4; r++) o[df][r] *= sc[r];
        }
        // P -> LDS (C-layout -> [q][key])
#pragma unroll
        for (int cf = 0; cf < 4; cf++) {
#pragma unroll
            for (int r = 0; r < 4; r++) Ps[w][fg * 4 + r][cf * 16 + fr] = f2bf(s[cf][r]);
        }
        // PV: O[q][d] += P[q][k] * V[k][d]; A = Ps rows, B = Vt rows (d), k contiguous
        bh8 pa0 = *(const bh8*)&Ps[w][fr][fg * 8];
        bh8 pa1 = *(const bh8*)&Ps[w][fr][32 + fg * 8];
#pragma unroll
        for (int df = 0; df < 4; df++) {
            bh8 vb0 = *(const bh8*)&Vt[df * 16 + fr][fg * 8];
            bh8 vb1 = *(const bh8*)&Vt[df * 16 + fr][32 + fg * 8];
            o[df] = __builtin_amdgcn_mfma_f32_16x16x32_bf16(pa0, vb0, o[df], 0, 0, 0);
            o[df] = __builtin_amdgcn_mfma_f32_16x16x32_bf16(pa1, vb1, o[df], 0, 0, 0);
        }
    }
    // epilogue: O /= l, write [B,S,H,DH]
#pragma unroll
    for (int df = 0; df < 4; df++) {
#pragma unroll
        for (int r = 0; r < 4; r++) {
            int q = qt * 64 + w * 16 + fg * 4 + r;
            float v = o[df][r] / l[r];
            ctxb[(((size_t)b * SS + q) * HH + h) * DH + df * 16 + fr] = f2bf(v);
        }
    }
}

// ---------------- gather classifier rows (s in [64,1024)) into compact [7680,768] bf16 ----------------
__global__ void gather_rows(const unsigned short* __restrict__ hb, unsigned short* __restrict__ hc) {
    int idx = blockIdx.x * 256 + threadIdx.x;   // chunk of 8
    if (idx >= NROWS * (DD / 8)) return;
    int g = idx / (DD / 8), c8 = (idx % (DD / 8)) * 8;
    int b = g / CLEN, cc = g % CLEN;
    *(bh8*)&hc[(size_t)g * DD + c8] = *(const bh8*)&hb[((size_t)(b * SS + 64 + cc)) * DD + c8];
}

// ---------------- classifier logsumexp state ----------------
__global__ void init_state(float* stM, float* stS, float* stT) {
    int i = blockIdx.x * 256 + threadIdx.x;
    if (i < NROWS) { stM[i] = -3e38f; stS[i] = 0.f; stT[i] = 0.f; }
}

__global__ __launch_bounds__(256) void lse_merge(const unsigned short* __restrict__ lchunk,
                                                 const int* __restrict__ y,
                                                 float* __restrict__ stM, float* __restrict__ stS,
                                                 float* __restrict__ stT, int c0, int cn) {
    int row = blockIdx.x, tid = threadIdx.x;
    int yv = y[row];
    int tloc = yv - c0;
    const unsigned short* lr = lchunk + (size_t)row * cn;
    float mx = -3e38f, sm = 0.f, tl = 0.f;
    for (int c = tid * 8; c < cn; c += 2048) {
        bh8 lv = *(const bh8*)&lr[c];
#pragma unroll
        for (int u = 0; u < 8; u++) {
            float d = bf2f((unsigned short)lv[u]);
            float m2 = fmaxf(mx, d);
            sm = sm * __expf(mx - m2) + __expf(d - m2);
            mx = m2;
            if (c + u == tloc) tl = d;
        }
    }
    __shared__ float red[4];
    float m = mx;
#pragma unroll
    for (int o = 32; o; o >>= 1) m = fmaxf(m, __shfl_down(m, o));
    if ((tid & 63) == 0) red[tid >> 6] = m;
    __syncthreads();
    float gmax = fmaxf(fmaxf(red[0], red[1]), fmaxf(red[2], red[3]));
    __syncthreads();
    float s = sm * __expf(mx - gmax);
#pragma unroll
    for (int o = 32; o; o >>= 1) s += __shfl_down(s, o);
    if ((tid & 63) == 0) red[tid >> 6] = s;
    __syncthreads();
    float gsum = red[0] + red[1] + red[2] + red[3];
    __syncthreads();
    float t = tl;
#pragma unroll
    for (int o = 32; o; o >>= 1) t += __shfl_down(t, o);
    if ((tid & 63) == 0) red[tid >> 6] = t;
    __syncthreads();
    float gt = red[0] + red[1] + red[2] + red[3];
    if (tid == 0) {
        float M0 = stM[row], S0 = stS[row];
        float M = fmaxf(M0, gmax);
        float S = S0 * __expf(M0 - M) + gsum * __expf(gmax - M);
        stM[row] = M;
        stS[row] = S;
        if (tloc >= 0 && tloc < cn) stT[row] = gt;
    }
}

__global__ __launch_bounds__(256) void final_reduce(const float* __restrict__ stM, const float* __restrict__ stS,
                                                    const float* __restrict__ stT, const int* __restrict__ y,
                                                    float* __restrict__ out) {
    int tid = threadIdx.x;
    float s = 0.f, c = 0.f;
    for (int i = tid; i < NROWS; i += 256) {
        if (y[i] != -100) {
            s += stM[i] + logf(stS[i]) - stT[i];
            c += 1.f;
        }
    }
    __shared__ float red[4];
    float gs = bsum256(s, red);
    float gc = bsum256(c, red);
    if (tid == 0) out[0] = gs / fmaxf(gc, 1.f);
}

// ---------------- launcher ----------------
extern "C" void kernel_launch(void* const* d_in, const int* in_sizes, int n_in,
                              void* d_out, int out_size, void* d_ws, size_t ws_size,
                              hipStream_t stream) {
    const int* x = (const int*)d_in[0];
    const int* y = (const int*)d_in[1];
    const float* we = (const float*)d_in[2];
    const float* pe = (const float*)d_in[3];
    const float* te = (const float*)d_in[4];
    const float* eg = (const float*)d_in[5];
    const float* eb = (const float*)d_in[6];
    const float* Wq = (const float*)d_in[7];
    const float* bq = (const float*)d_in[8];
    const float* Wk = (const float*)d_in[9];
    const float* bk = (const float*)d_in[10];
    const float* Wv = (const float*)d_in[11];
    const float* bv = (const float*)d_in[12];
    const float* Wo = (const float*)d_in[13];
    const float* bo = (const float*)d_in[14];
    const float* g1 = (const float*)d_in[15];
    const float* b1n = (const float*)d_in[16];
    const float* W1 = (const float*)d_in[17];
    const float* b1 = (const float*)d_in[18];
    const float* W2 = (const float*)d_in[19];
    const float* b2 = (const float*)d_in[20];
    const float* g2 = (const float*)d_in[21];
    const float* b2n = (const float*)d_in[22];
    const float* clsW = (const float*)d_in[23];
    const float* clsb = (const float*)d_in[24];
    float* out = (float*)d_out;

    char* ws = (char*)d_ws;
    size_t off = 0;
    auto alloc = [&](size_t n) {
        void* p = ws + off;
        off += n;
        off = (off + 255) & ~(size_t)255;
        return p;
    };
    float* h   = (float*)alloc((size_t)TOKS * DD * 4);
    float* h1  = (float*)alloc((size_t)TOKS * DD * 4);
    float* tmp = (float*)alloc((size_t)TOKS * DD * 4);
    unsigned short* hb   = (unsigned short*)alloc((size_t)TOKS * DD * 2);
    unsigned short* h1b  = (unsigned short*)alloc((size_t)TOKS * DD * 2);
    unsigned short* qbuf = (unsigned short*)alloc((size_t)TOKS * DD * 2);
    unsigned short* kbuf = (unsigned short*)alloc((size_t)TOKS * DD * 2);
    unsigned short* vbuf = (unsigned short*)alloc((size_t)TOKS * DD * 2);
    unsigned short* ctxb = (unsigned short*)alloc((size_t)TOKS * DD * 2);
    unsigned short* ffnb = (unsigned short*)alloc((size_t)TOKS * FF * 2);
    unsigned short* wqT = (unsigned short*)alloc((size_t)DD * DD * 2);
    unsigned short* wkT = (unsigned short*)alloc((size_t)DD * DD * 2);
    unsigned short* wvT = (unsigned short*)alloc((size_t)DD * DD * 2);
    unsigned short* woT = (unsigned short*)alloc((size_t)DD * DD * 2);
    unsigned short* w1T = (unsigned short*)alloc((size_t)DD * FF * 2);
    unsigned short* w2T = (unsigned short*)alloc((size_t)DD * FF * 2);
    unsigned short* clsT = (unsigned short*)alloc((size_t)VV * DD * 2);
    unsigned short* hc = (unsigned short*)alloc((size_t)NROWS * DD * 2);
    unsigned short* lchunk = (unsigned short*)alloc((size_t)NROWS * CHUNK * 2);
    float* stM = (float*)alloc(NROWS * 4);
    float* stS = (float*)alloc(NROWS * 4);
    float* stT = (float*)alloc(NROWS * 4);

    dim3 tb(32, 8);
    // classifier weight transpose: clsW [768, 21128] -> clsT [21128, 768]
    transpose_f32_bf16<<<dim3((VV + 31) / 32, DD / 32), tb, 0, stream>>>(clsW, clsT, DD, VV);
    // embedding
    embed_ln<<<TOKS, 256, 0, stream>>>(x, we, pe, te, eg, eb, h, hb);

    for (int l = 0; l < LL; l++) {
        const float* Wq_l = Wq + (size_t)l * DD * DD;
        const float* Wk_l = Wk + (size_t)l * DD * DD;
        const float* Wv_l = Wv + (size_t)l * DD * DD;
        const float* Wo_l = Wo + (size_t)l * DD * DD;
        const float* W1_l = W1 + (size_t)l * DD * FF;
        const float* W2_l = W2 + (size_t)l * FF * DD;
        transpose_f32_bf16<<<dim3(DD / 32, DD / 32), tb, 0, stream>>>(Wq_l, wqT, DD, DD);
        transpose_f32_bf16<<<dim3(DD / 32, DD / 32), tb, 0, stream>>>(Wk_l, wkT, DD, DD);
        transpose_f32_bf16<<<dim3(DD / 32, DD / 32), tb, 0, stream>>>(Wv_l, wvT, DD, DD);
        transpose_f32_bf16<<<dim3(DD / 32, DD / 32), tb, 0, stream>>>(Wo_l, woT, DD, DD);
        transpose_f32_bf16<<<dim3(FF / 32, DD / 32), tb, 0, stream>>>(W1_l, w1T, DD, FF);
        transpose_f32_bf16<<<dim3(DD / 32, FF / 32), tb, 0, stream>>>(W2_l, w2T, FF, DD);

        dim3 gqkv(DD / 64, TOKS / 64);
        gemm_bt<1><<<gqkv, 256, 0, stream>>>(hb, wqT, bq + (size_t)l * DD, qbuf, TOKS, DD, DD);
        gemm_bt<1><<<gqkv, 256, 0, stream>>>(hb, wkT, bk + (size_t)l * DD, kbuf, TOKS, DD, DD);
        gemm_bt<1><<<gqkv, 256, 0, stream>>>(hb, wvT, bv + (size_t)l * DD, vbuf, TOKS, DD, DD);

        flash_attn<<<dim3(SS / 64, HH, BB), 256, 0, stream>>>(qbuf, kbuf, vbuf, ctxb);

        gemm_bt<0><<<gqkv, 256, 0, stream>>>(ctxb, woT, bo + (size_t)l * DD, tmp, TOKS, DD, DD);
        add_ln<<<TOKS, 256, 0, stream>>>(h, tmp, g1 + (size_t)l * DD, b1n + (size_t)l * DD, h1, h1b);

        gemm_bt<2><<<dim3(FF / 64, TOKS / 64), 256, 0, stream>>>(h1b, w1T, b1 + (size_t)l * FF, ffnb, TOKS, FF, DD);
        gemm_bt<0><<<gqkv, 256, 0, stream>>>(ffnb, w2T, b2 + (size_t)l * DD, tmp, TOKS, DD, FF);
        add_ln<<<TOKS, 256, 0, stream>>>(h1, tmp, g2 + (size_t)l * DD, b2n + (size_t)l * DD, h, hb);
    }

    // classifier
    gather_rows<<<(NROWS * (DD / 8) + 255) / 256, 256, 0, stream>>>(hb, hc);
    init_state<<<(NROWS + 255) / 256, 256, 0, stream>>>(stM, stS, stT);
    for (int c0 = 0; c0 < VV; c0 += CHUNK) {
        int cn = VV - c0 < CHUNK ? VV - c0 : CHUNK;
        dim3 gc((cn + 63) / 64, NROWS / 64);
        gemm_bt<1><<<gc, 256, 0, stream>>>(hc, clsT + (size_t)c0 * DD, clsb + c0, lchunk, NROWS, cn, DD);
        lse_merge<<<NROWS, 256, 0, stream>>>(lchunk, y, stM, stS, stT, c0, cn);
    }
    final_reduce<<<1, 256, 0, stream>>>(stM, stS, stT, y, out);
}

// Round 3
// 5164.633 us; speedup vs baseline: 5.6588x; 1.2700x over previous
//
#include <hip/hip_runtime.h>

#define BB 8
#define SS 1024
#define LL 12
#define DD 768
#define HH 12
#define FF 3072
#define VV 21128
#define DH 64
#define CLEN 960
#define NROWS (BB * CLEN)        // 7680 classifier rows
#define TOKS (BB * SS)           // 8192 token rows
#define CHUNK 2048               // classifier column chunk
#define NQKV 2304                // fused QKV output width

typedef __attribute__((ext_vector_type(8))) short bh8;
typedef __attribute__((ext_vector_type(4))) float f32x4;
typedef __attribute__((ext_vector_type(4))) unsigned short us4;

__device__ __forceinline__ float bf2f(unsigned short u) {
    union { unsigned int i; float f; } c; c.i = ((unsigned int)u) << 16; return c.f;
}
__device__ __forceinline__ unsigned short f2bf(float f) {
    union { float f; unsigned int i; } c; c.f = f;
    unsigned int r = c.i + 0x7fffu + ((c.i >> 16) & 1u);
    return (unsigned short)(r >> 16);
}

#define GLOAD16(gsrc, ldst)                                                              \
    __builtin_amdgcn_global_load_lds((const __attribute__((address_space(1))) unsigned int*)(gsrc), \
                                     (__attribute__((address_space(3))) unsigned int*)(ldst), 16, 0, 0)

// 256-thread block sum; red must be shared float[4]
__device__ __forceinline__ float bsum256(float v, float* red) {
#pragma unroll
    for (int o = 32; o; o >>= 1) v += __shfl_down(v, o);
    if ((threadIdx.x & 63) == 0) red[threadIdx.x >> 6] = v;
    __syncthreads();
    float r = red[0] + red[1] + red[2] + red[3];
    __syncthreads();
    return r;
}

// ---------------- transpose fp32 [R,C] -> bf16 [C,R] ----------------
__global__ void transpose_f32_bf16(const float* __restrict__ in, unsigned short* __restrict__ out,
                                   int R, int C) {
    __shared__ float tile[32][33];
    int c0 = blockIdx.x << 5, r0 = blockIdx.y << 5;
    int tx = threadIdx.x, ty = threadIdx.y;
    for (int i = ty; i < 32; i += 8) {
        int r = r0 + i, c = c0 + tx;
        if (r < R && c < C) tile[i][tx] = in[(size_t)r * C + c];
    }
    __syncthreads();
    for (int i = ty; i < 32; i += 8) {
        int oc = c0 + i, orr = r0 + tx;
        if (oc < C && orr < R) out[(size_t)oc * R + orr] = f2bf(tile[tx][i]);
    }
}

__global__ void concat_bias(const float* __restrict__ bq, const float* __restrict__ bk,
                            const float* __restrict__ bv, float* __restrict__ out) {
    int i = blockIdx.x * 256 + threadIdx.x;
    if (i < DD) out[i] = bq[i];
    else if (i < 2 * DD) out[i] = bk[i - DD];
    else if (i < 3 * DD) out[i] = bv[i - 2 * DD];
}

// ---------------- embedding + LN ----------------
__global__ __launch_bounds__(256) void embed_ln(const int* __restrict__ x, const float* __restrict__ we,
                                                const float* __restrict__ pe, const float* __restrict__ te,
                                                const float* __restrict__ g, const float* __restrict__ be,
                                                float* __restrict__ hf, unsigned short* __restrict__ hb) {
    int row = blockIdx.x;            // b*S + s
    int s = row & (SS - 1);
    int tok = x[row];
    int tid = threadIdx.x;
    __shared__ float red[4];
    float v[3];
#pragma unroll
    for (int i = 0; i < 3; i++) {
        int c = tid + i * 256;
        v[i] = we[(size_t)tok * DD + c] + pe[(size_t)s * DD + c] + te[c];
    }
    float mean = bsum256(v[0] + v[1] + v[2], red) * (1.f / DD);
    float d0 = v[0] - mean, d1 = v[1] - mean, d2 = v[2] - mean;
    float var = bsum256(d0 * d0 + d1 * d1 + d2 * d2, red) * (1.f / DD);
    float inv = rsqrtf(var + 1e-12f);
    size_t base = (size_t)row * DD;
#pragma unroll
    for (int i = 0; i < 3; i++) {
        int c = tid + i * 256;
        float o = (v[i] - mean) * inv * g[c] + be[c];
        hf[base + c] = o;
        hb[base + c] = f2bf(o);
    }
}

// ---------------- residual add + LN (dual output) ----------------
__global__ __launch_bounds__(256) void add_ln(const float* __restrict__ res, const float* __restrict__ t,
                                              const float* __restrict__ g, const float* __restrict__ be,
                                              float* __restrict__ outf, unsigned short* __restrict__ outb) {
    int row = blockIdx.x;
    int tid = threadIdx.x;
    __shared__ float red[4];
    size_t base = (size_t)row * DD;
    float v[3];
#pragma unroll
    for (int i = 0; i < 3; i++) {
        int c = tid + i * 256;
        v[i] = res[base + c] + t[base + c];
    }
    float mean = bsum256(v[0] + v[1] + v[2], red) * (1.f / DD);
    float d0 = v[0] - mean, d1 = v[1] - mean, d2 = v[2] - mean;
    float var = bsum256(d0 * d0 + d1 * d1 + d2 * d2, red) * (1.f / DD);
    float inv = rsqrtf(var + 1e-12f);
#pragma unroll
    for (int i = 0; i < 3; i++) {
        int c = tid + i * 256;
        float o = (v[i] - mean) * inv * g[c] + be[c];
        outf[base + c] = o;
        outb[base + c] = f2bf(o);
    }
}

// ---------------- m97-style MFMA GEMM: 128x128 tile, BK=32, global_load_lds ----------------
// C[M,N] = A[M,K] * BT[N,K]^T + bias
// MODE 0: fp32 out; 1: bf16 out; 2: bf16 + exact GELU; 4: fused QKV epilogue
// (cols <1536 -> Cb[token*1536+col]; cols >=1536 -> V^T [B,H,DH,S] via vt_out)
template <int MODE>
__global__ __launch_bounds__(256) void gemm128(const unsigned short* __restrict__ A,
                                               const unsigned short* __restrict__ BT,
                                               const float* __restrict__ bias, void* __restrict__ Cp,
                                               int M, int N, int K, int ldc,
                                               unsigned short* __restrict__ vt_out) {
    __shared__ __align__(16) unsigned short As[128 * 32];
    __shared__ __align__(16) unsigned short Bs[128 * 32];
    const int tid = threadIdx.x;
    const int lane = tid & 63, w = tid >> 6;
    const int fr = lane & 15, fg = lane >> 4;
    const int wr = w >> 1, wc = w & 1;
    const int m0 = blockIdx.y << 7, n0 = blockIdx.x << 7;
    const int srow = lane >> 2;          // 0..15
    const int skcol = (lane & 3) << 3;   // 0,8,16,24

    // per-lane global row indices for the 2 staging chunks of A and B
    int arow0 = m0 + (w * 2 + 0) * 16 + srow;
    int arow1 = m0 + (w * 2 + 1) * 16 + srow;
    int brow0 = n0 + (w * 2 + 0) * 16 + srow;
    int brow1 = n0 + (w * 2 + 1) * 16 + srow;
    if (brow0 >= N) brow0 = N - 1;       // clamp (classifier tail); C-write guarded
    if (brow1 >= N) brow1 = N - 1;
    const unsigned short* aptr0 = A + (size_t)arow0 * K + skcol;
    const unsigned short* aptr1 = A + (size_t)arow1 * K + skcol;
    const unsigned short* bptr0 = BT + (size_t)brow0 * K + skcol;
    const unsigned short* bptr1 = BT + (size_t)brow1 * K + skcol;
    unsigned short* lA0 = &As[(w * 2 + 0) * 512];
    unsigned short* lA1 = &As[(w * 2 + 1) * 512];
    unsigned short* lB0 = &Bs[(w * 2 + 0) * 512];
    unsigned short* lB1 = &Bs[(w * 2 + 1) * 512];

    f32x4 acc[4][4] = {};
    for (int k0 = 0; k0 < K; k0 += 32) {
        __syncthreads();
        GLOAD16(aptr0 + k0, lA0);
        GLOAD16(aptr1 + k0, lA1);
        GLOAD16(bptr0 + k0, lB0);
        GLOAD16(bptr1 + k0, lB1);
        __syncthreads();
        bh8 a[4], b[4];
#pragma unroll
        for (int mi = 0; mi < 4; mi++) a[mi] = *(const bh8*)&As[(wr * 64 + mi * 16 + fr) * 32 + fg * 8];
#pragma unroll
        for (int ni = 0; ni < 4; ni++) b[ni] = *(const bh8*)&Bs[(wc * 64 + ni * 16 + fr) * 32 + fg * 8];
        __builtin_amdgcn_s_setprio(1);
#pragma unroll
        for (int mi = 0; mi < 4; mi++)
#pragma unroll
            for (int ni = 0; ni < 4; ni++)
                acc[mi][ni] = __builtin_amdgcn_mfma_f32_16x16x32_bf16(a[mi], b[ni], acc[mi][ni], 0, 0, 0);
        __builtin_amdgcn_s_setprio(0);
    }

    float* Cf = (float*)Cp;
    unsigned short* Cb = (unsigned short*)Cp;
#pragma unroll
    for (int mi = 0; mi < 4; mi++) {
#pragma unroll
        for (int ni = 0; ni < 4; ni++) {
            int col = n0 + wc * 64 + ni * 16 + fr;
            int rbase = m0 + wr * 64 + mi * 16 + fg * 4;
            if (MODE == 4) {
                float bb = bias[col];
                if (col < 2 * DD) {
#pragma unroll
                    for (int r = 0; r < 4; r++)
                        Cb[(size_t)(rbase + r) * (2 * DD) + col] = f2bf(acc[mi][ni][r] + bb);
                } else {
                    int g = col - 2 * DD, h = g >> 6, d = g & 63;
                    int bi = rbase >> 10, s0 = rbase & 1023;
                    us4 val;
#pragma unroll
                    for (int r = 0; r < 4; r++) val[r] = f2bf(acc[mi][ni][r] + bb);
                    *(us4*)&vt_out[(((size_t)bi * HH + h) * DH + d) * SS + s0] = val;
                }
            } else if (col < N) {
                float bb = bias[col];
#pragma unroll
                for (int r = 0; r < 4; r++) {
                    float v = acc[mi][ni][r] + bb;
                    if (MODE == 2) v = 0.5f * v * (1.0f + erff(v * 0.70710678118f));
                    if (MODE == 0) Cf[(size_t)(rbase + r) * ldc + col] = v;
                    else Cb[(size_t)(rbase + r) * ldc + col] = f2bf(v);
                }
            }
        }
    }
}

// ---------------- flash attention: grid (S/64, H, B), 4 waves, 16 Q-rows/wave ----------------
// Q,K from fused qkbuf [B*S, 1536] (Q cols h*64.., K cols 768+h*64..); V from VT [B,H,DH,S]
__global__ __launch_bounds__(256) void flash_attn(const unsigned short* __restrict__ qkbuf,
                                                  const unsigned short* __restrict__ VT,
                                                  unsigned short* __restrict__ ctxb) {
    const int qt = blockIdx.x, h = blockIdx.y, b = blockIdx.z;
    const int tid = threadIdx.x;
    const int lane = tid & 63, w = tid >> 6;
    const int fr = lane & 15, fg = lane >> 4;
    __shared__ unsigned short Qs[64][72];
    __shared__ unsigned short Ks[64][72];
    __shared__ unsigned short Vt[64][72];       // Vt[d][key]
    __shared__ unsigned short Ps[4][16][72];    // per-wave P [q][key]

    // stage Q tile
    {
        int row = tid >> 2, d0 = (tid & 3) << 4;
        const unsigned short* src = qkbuf + (size_t)(b * SS + qt * 64 + row) * (2 * DD) + h * 64 + d0;
        *(bh8*)&Qs[row][d0] = *(const bh8*)src;
        *(bh8*)&Qs[row][d0 + 8] = *(const bh8*)(src + 8);
    }

    f32x4 o[4] = {};
    float m[4], l[4];
#pragma unroll
    for (int r = 0; r < 4; r++) { m[r] = -3e30f; l[r] = 0.f; }

    const int nkt = (qt == 0) ? 1 : qt + 1;
    for (int kt = 0; kt < nkt; kt++) {
        __syncthreads();
        {
            int row = tid >> 2, d0 = (tid & 3) << 4;
            const unsigned short* ksrc = qkbuf + (size_t)(b * SS + kt * 64 + row) * (2 * DD) + DD + h * 64 + d0;
            *(bh8*)&Ks[row][d0] = *(const bh8*)ksrc;
            *(bh8*)&Ks[row][d0 + 8] = *(const bh8*)(ksrc + 8);
            // V^T tile: rows d, cols key
            const unsigned short* vsrc = VT + (((size_t)b * HH + h) * DH + row) * SS + qt * 0 + kt * 64 + d0;
            *(bh8*)&Vt[row][d0] = *(const bh8*)vsrc;
            *(bh8*)&Vt[row][d0 + 8] = *(const bh8*)(vsrc + 8);
        }
        __syncthreads();

        // QK^T
        f32x4 s[4] = {};
        bh8 a0 = *(const bh8*)&Qs[w * 16 + fr][fg * 8];
        bh8 a1 = *(const bh8*)&Qs[w * 16 + fr][32 + fg * 8];
        __builtin_amdgcn_s_setprio(1);
#pragma unroll
        for (int cf = 0; cf < 4; cf++) {
            bh8 b0 = *(const bh8*)&Ks[cf * 16 + fr][fg * 8];
            bh8 b1 = *(const bh8*)&Ks[cf * 16 + fr][32 + fg * 8];
            s[cf] = __builtin_amdgcn_mfma_f32_16x16x32_bf16(a0, b0, s[cf], 0, 0, 0);
            s[cf] = __builtin_amdgcn_mfma_f32_16x16x32_bf16(a1, b1, s[cf], 0, 0, 0);
        }
        __builtin_amdgcn_s_setprio(0);
        const bool diag = (qt > 0) && (kt == qt);
#pragma unroll
        for (int cf = 0; cf < 4; cf++) {
#pragma unroll
            for (int r = 0; r < 4; r++) {
                float v = s[cf][r] * 0.125f;
                if (diag) {
                    int key = cf * 16 + fr;
                    int qrow = w * 16 + fg * 4 + r;
                    if (key > qrow) v = -1e30f;
                }
                s[cf][r] = v;
            }
        }
        float ps[4], sc[4], mn[4];
#pragma unroll
        for (int r = 0; r < 4; r++) {
            float v = fmaxf(fmaxf(s[0][r], s[1][r]), fmaxf(s[2][r], s[3][r]));
#pragma unroll
            for (int off = 1; off < 16; off <<= 1) v = fmaxf(v, __shfl_xor(v, off));
            mn[r] = fmaxf(m[r], v);
            sc[r] = __expf(m[r] - mn[r]);
            m[r] = mn[r];
        }
#pragma unroll
        for (int cf = 0; cf < 4; cf++) {
#pragma unroll
            for (int r = 0; r < 4; r++) s[cf][r] = __expf(s[cf][r] - mn[r]);
        }
#pragma unroll
        for (int r = 0; r < 4; r++) {
            float v = s[0][r] + s[1][r] + s[2][r] + s[3][r];
#pragma unroll
            for (int off = 1; off < 16; off <<= 1) v += __shfl_xor(v, off);
            ps[r] = v;
            l[r] = l[r] * sc[r] + ps[r];
        }
#pragma unroll
        for (int df = 0; df < 4; df++) {
#pragma unroll
            for (int r = 0; r < 4; r++) o[df][r] *= sc[r];
        }
#pragma unroll
        for (int cf = 0; cf < 4; cf++) {
#pragma unroll
            for (int r = 0; r < 4; r++) Ps[w][fg * 4 + r][cf * 16 + fr] = f2bf(s[cf][r]);
        }
        bh8 pa0 = *(const bh8*)&Ps[w][fr][fg * 8];
        bh8 pa1 = *(const bh8*)&Ps[w][fr][32 + fg * 8];
        __builtin_amdgcn_s_setprio(1);
#pragma unroll
        for (int df = 0; df < 4; df++) {
            bh8 vb0 = *(const bh8*)&Vt[df * 16 + fr][fg * 8];
            bh8 vb1 = *(const bh8*)&Vt[df * 16 + fr][32 + fg * 8];
            o[df] = __builtin_amdgcn_mfma_f32_16x16x32_bf16(pa0, vb0, o[df], 0, 0, 0);
            o[df] = __builtin_amdgcn_mfma_f32_16x16x32_bf16(pa1, vb1, o[df], 0, 0, 0);
        }
        __builtin_amdgcn_s_setprio(0);
    }
#pragma unroll
    for (int df = 0; df < 4; df++) {
#pragma unroll
        for (int r = 0; r < 4; r++) {
            int q = qt * 64 + w * 16 + fg * 4 + r;
            float v = o[df][r] / l[r];
            ctxb[(((size_t)b * SS + q) * HH + h) * DH + df * 16 + fr] = f2bf(v);
        }
    }
}

// ---------------- gather classifier rows (s in [64,1024)) into compact [7680,768] bf16 ----------------
__global__ void gather_rows(const unsigned short* __restrict__ hb, unsigned short* __restrict__ hc) {
    int idx = blockIdx.x * 256 + threadIdx.x;
    if (idx >= NROWS * (DD / 8)) return;
    int g = idx / (DD / 8), c8 = (idx % (DD / 8)) * 8;
    int b = g / CLEN, cc = g % CLEN;
    *(bh8*)&hc[(size_t)g * DD + c8] = *(const bh8*)&hb[((size_t)(b * SS + 64 + cc)) * DD + c8];
}

// ---------------- classifier logsumexp state ----------------
__global__ void init_state(float* stM, float* stS, float* stT) {
    int i = blockIdx.x * 256 + threadIdx.x;
    if (i < NROWS) { stM[i] = -3e38f; stS[i] = 0.f; stT[i] = 0.f; }
}

__global__ __launch_bounds__(256) void lse_merge(const unsigned short* __restrict__ lchunk,
                                                 const int* __restrict__ y,
                                                 float* __restrict__ stM, float* __restrict__ stS,
                                                 float* __restrict__ stT, int c0, int cn) {
    int row = blockIdx.x, tid = threadIdx.x;
    int yv = y[row];
    int tloc = yv - c0;
    const unsigned short* lr = lchunk + (size_t)row * cn;
    float mx = -3e38f, sm = 0.f, tl = 0.f;
    for (int c = tid * 8; c < cn; c += 2048) {
        bh8 lv = *(const bh8*)&lr[c];
#pragma unroll
        for (int u = 0; u < 8; u++) {
            float d = bf2f((unsigned short)lv[u]);
            float m2 = fmaxf(mx, d);
            sm = sm * __expf(mx - m2) + __expf(d - m2);
            mx = m2;
            if (c + u == tloc) tl = d;
        }
    }
    __shared__ float red[4];
    float m = mx;
#pragma unroll
    for (int o = 32; o; o >>= 1) m = fmaxf(m, __shfl_down(m, o));
    if ((tid & 63) == 0) red[tid >> 6] = m;
    __syncthreads();
    float gmax = fmaxf(fmaxf(red[0], red[1]), fmaxf(red[2], red[3]));
    __syncthreads();
    float s = sm * __expf(mx - gmax);
#pragma unroll
    for (int o = 32; o; o >>= 1) s += __shfl_down(s, o);
    if ((tid & 63) == 0) red[tid >> 6] = s;
    __syncthreads();
    float gsum = red[0] + red[1] + red[2] + red[3];
    __syncthreads();
    float t = tl;
#pragma unroll
    for (int o = 32; o; o >>= 1) t += __shfl_down(t, o);
    if ((tid & 63) == 0) red[tid >> 6] = t;
    __syncthreads();
    float gt = red[0] + red[1] + red[2] + red[3];
    if (tid == 0) {
        float M0 = stM[row], S0 = stS[row];
        float M = fmaxf(M0, gmax);
        float S = S0 * __expf(M0 - M) + gsum * __expf(gmax - M);
        stM[row] = M;
        stS[row] = S;
        if (tloc >= 0 && tloc < cn) stT[row] = gt;
    }
}

__global__ __launch_bounds__(256) void final_reduce(const float* __restrict__ stM, const float* __restrict__ stS,
                                                    const float* __restrict__ stT, const int* __restrict__ y,
                                                    float* __restrict__ out) {
    int tid = threadIdx.x;
    float s = 0.f, c = 0.f;
    for (int i = tid; i < NROWS; i += 256) {
        if (y[i] != -100) {
            s += stM[i] + logf(stS[i]) - stT[i];
            c += 1.f;
        }
    }
    __shared__ float red[4];
    float gs = bsum256(s, red);
    float gc = bsum256(c, red);
    if (tid == 0) out[0] = gs / fmaxf(gc, 1.f);
}

// ---------------- launcher ----------------
extern "C" void kernel_launch(void* const* d_in, const int* in_sizes, int n_in,
                              void* d_out, int out_size, void* d_ws, size_t ws_size,
                              hipStream_t stream) {
    const int* x = (const int*)d_in[0];
    const int* y = (const int*)d_in[1];
    const float* we = (const float*)d_in[2];
    const float* pe = (const float*)d_in[3];
    const float* te = (const float*)d_in[4];
    const float* eg = (const float*)d_in[5];
    const float* eb = (const float*)d_in[6];
    const float* Wq = (const float*)d_in[7];
    const float* bq = (const float*)d_in[8];
    const float* Wk = (const float*)d_in[9];
    const float* bk = (const float*)d_in[10];
    const float* Wv = (const float*)d_in[11];
    const float* bv = (const float*)d_in[12];
    const float* Wo = (const float*)d_in[13];
    const float* bo = (const float*)d_in[14];
    const float* g1 = (const float*)d_in[15];
    const float* b1n = (const float*)d_in[16];
    const float* W1 = (const float*)d_in[17];
    const float* b1 = (const float*)d_in[18];
    const float* W2 = (const float*)d_in[19];
    const float* b2 = (const float*)d_in[20];
    const float* g2 = (const float*)d_in[21];
    const float* b2n = (const float*)d_in[22];
    const float* clsW = (const float*)d_in[23];
    const float* clsb = (const float*)d_in[24];
    float* out = (float*)d_out;

    char* ws = (char*)d_ws;
    size_t off = 0;
    auto alloc = [&](size_t n) {
        void* p = ws + off;
        off += n;
        off = (off + 255) & ~(size_t)255;
        return p;
    };
    float* h   = (float*)alloc((size_t)TOKS * DD * 4);
    float* h1  = (float*)alloc((size_t)TOKS * DD * 4);
    float* tmp = (float*)alloc((size_t)TOKS * DD * 4);
    unsigned short* hb   = (unsigned short*)alloc((size_t)TOKS * DD * 2);
    unsigned short* h1b  = (unsigned short*)alloc((size_t)TOKS * DD * 2);
    unsigned short* qkbuf = (unsigned short*)alloc((size_t)TOKS * 2 * DD * 2);
    unsigned short* vtb  = (unsigned short*)alloc((size_t)TOKS * DD * 2);
    unsigned short* ctxb = (unsigned short*)alloc((size_t)TOKS * DD * 2);
    unsigned short* ffnb = (unsigned short*)alloc((size_t)TOKS * FF * 2);
    unsigned short* wqkvT = (unsigned short*)alloc((size_t)NQKV * DD * 2);
    unsigned short* woT = (unsigned short*)alloc((size_t)DD * DD * 2);
    unsigned short* w1T = (unsigned short*)alloc((size_t)DD * FF * 2);
    unsigned short* w2T = (unsigned short*)alloc((size_t)DD * FF * 2);
    unsigned short* clsT = (unsigned short*)alloc((size_t)VV * DD * 2);
    unsigned short* hc = (unsigned short*)alloc((size_t)NROWS * DD * 2);
    unsigned short* lchunk = (unsigned short*)alloc((size_t)NROWS * CHUNK * 2);
    float* bqkv = (float*)alloc(NQKV * 4);
    float* stM = (float*)alloc(NROWS * 4);
    float* stS = (float*)alloc(NROWS * 4);
    float* stT = (float*)alloc(NROWS * 4);

    dim3 tb(32, 8);
    transpose_f32_bf16<<<dim3((VV + 31) / 32, DD / 32), tb, 0, stream>>>(clsW, clsT, DD, VV);
    embed_ln<<<TOKS, 256, 0, stream>>>(x, we, pe, te, eg, eb, h, hb);

    for (int l = 0; l < LL; l++) {
        const float* Wq_l = Wq + (size_t)l * DD * DD;
        const float* Wk_l = Wk + (size_t)l * DD * DD;
        const float* Wv_l = Wv + (size_t)l * DD * DD;
        const float* Wo_l = Wo + (size_t)l * DD * DD;
        const float* W1_l = W1 + (size_t)l * DD * FF;
        const float* W2_l = W2 + (size_t)l * FF * DD;
        transpose_f32_bf16<<<dim3(DD / 32, DD / 32), tb, 0, stream>>>(Wq_l, wqkvT, DD, DD);
        transpose_f32_bf16<<<dim3(DD / 32, DD / 32), tb, 0, stream>>>(Wk_l, wqkvT + (size_t)DD * DD, DD, DD);
        transpose_f32_bf16<<<dim3(DD / 32, DD / 32), tb, 0, stream>>>(Wv_l, wqkvT + (size_t)2 * DD * DD, DD, DD);
        transpose_f32_bf16<<<dim3(DD / 32, DD / 32), tb, 0, stream>>>(Wo_l, woT, DD, DD);
        transpose_f32_bf16<<<dim3(FF / 32, DD / 32), tb, 0, stream>>>(W1_l, w1T, DD, FF);
        transpose_f32_bf16<<<dim3(DD / 32, FF / 32), tb, 0, stream>>>(W2_l, w2T, FF, DD);
        concat_bias<<<9, 256, 0, stream>>>(bq + (size_t)l * DD, bk + (size_t)l * DD, bv + (size_t)l * DD, bqkv);

        // fused QKV GEMM
        gemm128<4><<<dim3(NQKV / 128, TOKS / 128), 256, 0, stream>>>(hb, wqkvT, bqkv, qkbuf,
                                                                     TOKS, NQKV, DD, NQKV, vtb);

        flash_attn<<<dim3(SS / 64, HH, BB), 256, 0, stream>>>(qkbuf, vtb, ctxb);

        gemm128<0><<<dim3(DD / 128, TOKS / 128), 256, 0, stream>>>(ctxb, woT, bo + (size_t)l * DD, tmp,
                                                                   TOKS, DD, DD, DD, nullptr);
        add_ln<<<TOKS, 256, 0, stream>>>(h, tmp, g1 + (size_t)l * DD, b1n + (size_t)l * DD, h1, h1b);

        gemm128<2><<<dim3(FF / 128, TOKS / 128), 256, 0, stream>>>(h1b, w1T, b1 + (size_t)l * FF, ffnb,
                                                                   TOKS, FF, DD, FF, nullptr);
        gemm128<0><<<dim3(DD / 128, TOKS / 128), 256, 0, stream>>>(ffnb, w2T, b2 + (size_t)l * DD, tmp,
                                                                   TOKS, DD, FF, DD, nullptr);
        add_ln<<<TOKS, 256, 0, stream>>>(h1, tmp, g2 + (size_t)l * DD, b2n + (size_t)l * DD, h, hb);
    }

    gather_rows<<<(NROWS * (DD / 8) + 255) / 256, 256, 0, stream>>>(hb, hc);
    init_state<<<(NROWS + 255) / 256, 256, 0, stream>>>(stM, stS, stT);
    for (int c0 = 0; c0 < VV; c0 += CHUNK) {
        int cn = VV - c0 < CHUNK ? VV - c0 : CHUNK;
        gemm128<1><<<dim3((cn + 127) / 128, NROWS / 128), 256, 0, stream>>>(hc, clsT + (size_t)c0 * DD,
                                                                            clsb + c0, lchunk,
                                                                            NROWS, cn, DD, cn, nullptr);
        lse_merge<<<NROWS, 256, 0, stream>>>(lchunk, y, stM, stS, stT, c0, cn);
    }
    final_reduce<<<1, 256, 0, stream>>>(stM, stS, stT, y, out);
}

// Round 4
// 4989.065 us; speedup vs baseline: 5.8580x; 1.0352x over previous
//
#include <hip/hip_runtime.h>

#define BB 8
#define SS 1024
#define LL 12
#define DD 768
#define HH 12
#define FF 3072
#define VV 21128
#define DH 64
#define CLEN 960
#define NROWS (BB * CLEN)        // 7680 classifier rows
#define TOKS (BB * SS)           // 8192 token rows
#define CHUNK 2048               // classifier column chunk
#define NQKV 2304                // fused QKV output width

typedef __attribute__((ext_vector_type(8))) short bh8;
typedef __attribute__((ext_vector_type(4))) float f32x4;
typedef __attribute__((ext_vector_type(4))) unsigned short us4;

__device__ __forceinline__ float bf2f(unsigned short u) {
    union { unsigned int i; float f; } c; c.i = ((unsigned int)u) << 16; return c.f;
}
__device__ __forceinline__ unsigned short f2bf(float f) {
    union { float f; unsigned int i; } c; c.f = f;
    unsigned int r = c.i + 0x7fffu + ((c.i >> 16) & 1u);
    return (unsigned short)(r >> 16);
}

#define GLOAD16(gsrc, ldst)                                                              \
    __builtin_amdgcn_global_load_lds((const __attribute__((address_space(1))) unsigned int*)(gsrc), \
                                     (__attribute__((address_space(3))) unsigned int*)(ldst), 16, 0, 0)

// 256-thread block sum; red must be shared float[4]
__device__ __forceinline__ float bsum256(float v, float* red) {
#pragma unroll
    for (int o = 32; o; o >>= 1) v += __shfl_down(v, o);
    if ((threadIdx.x & 63) == 0) red[threadIdx.x >> 6] = v;
    __syncthreads();
    float r = red[0] + red[1] + red[2] + red[3];
    __syncthreads();
    return r;
}

// ---------------- transpose fp32 [R,C] -> bf16 [C,R] (classifier) ----------------
__global__ void transpose_f32_bf16(const float* __restrict__ in, unsigned short* __restrict__ out,
                                   int R, int C) {
    __shared__ float tile[32][33];
    int c0 = blockIdx.x << 5, r0 = blockIdx.y << 5;
    int tx = threadIdx.x, ty = threadIdx.y;
    for (int i = ty; i < 32; i += 8) {
        int r = r0 + i, c = c0 + tx;
        if (r < R && c < C) tile[i][tx] = in[(size_t)r * C + c];
    }
    __syncthreads();
    for (int i = ty; i < 32; i += 8) {
        int oc = c0 + i, orr = r0 + tx;
        if (oc < C && orr < R) out[(size_t)oc * R + orr] = f2bf(tile[tx][i]);
    }
}

// ---------------- batched per-layer weight transpose: 1 dispatch per layer ----------------
// segments (32x32 tiles): [0,1728) Wq/Wk/Wv -> wqkvT; [1728,2304) Wo -> woT;
// [2304,4608) W1[768,3072] -> w1T[3072][768]; [4608,6912) W2[3072,768] -> w2T[768][3072]
__global__ void transpose_layer(const float* __restrict__ Wq, const float* __restrict__ Wk,
                                const float* __restrict__ Wv, const float* __restrict__ Wo,
                                const float* __restrict__ W1, const float* __restrict__ W2,
                                unsigned short* __restrict__ wqkvT, unsigned short* __restrict__ woT,
                                unsigned short* __restrict__ w1T, unsigned short* __restrict__ w2T) {
    __shared__ float tile[32][33];
    int t = blockIdx.x;
    const float* src;
    unsigned short* dst;
    int R, C, txt, tt;
    if (t < 1728) {
        int which = t / 576; tt = t % 576;
        src = which == 0 ? Wq : (which == 1 ? Wk : Wv);
        dst = wqkvT + (size_t)which * DD * DD; R = DD; C = DD; txt = 24;
    } else if (t < 2304) {
        tt = t - 1728; src = Wo; dst = woT; R = DD; C = DD; txt = 24;
    } else if (t < 4608) {
        tt = t - 2304; src = W1; dst = w1T; R = DD; C = FF; txt = 96;
    } else {
        tt = t - 4608; src = W2; dst = w2T; R = FF; C = DD; txt = 24;
    }
    int c0 = (tt % txt) << 5, r0 = (tt / txt) << 5;
    int tx = threadIdx.x, ty = threadIdx.y;
    for (int i = ty; i < 32; i += 8) tile[i][tx] = src[(size_t)(r0 + i) * C + c0 + tx];
    __syncthreads();
    for (int i = ty; i < 32; i += 8) dst[(size_t)(c0 + i) * R + r0 + tx] = f2bf(tile[tx][i]);
}

// all-layer QKV bias concat: out[l][0:768)=bq[l], [768:1536)=bk[l], [1536:2304)=bv[l]
__global__ void concat_bias_all(const float* __restrict__ bq, const float* __restrict__ bk,
                                const float* __restrict__ bv, float* __restrict__ out) {
    int i = blockIdx.x * 256 + threadIdx.x;
    if (i >= LL * NQKV) return;
    int l = i / NQKV, c = i % NQKV;
    float v = c < DD ? bq[(size_t)l * DD + c]
                     : (c < 2 * DD ? bk[(size_t)l * DD + c - DD] : bv[(size_t)l * DD + c - 2 * DD]);
    out[i] = v;
}

// ---------------- embedding + LN ----------------
__global__ __launch_bounds__(256) void embed_ln(const int* __restrict__ x, const float* __restrict__ we,
                                                const float* __restrict__ pe, const float* __restrict__ te,
                                                const float* __restrict__ g, const float* __restrict__ be,
                                                float* __restrict__ hf, unsigned short* __restrict__ hb) {
    int row = blockIdx.x;            // b*S + s
    int s = row & (SS - 1);
    int tok = x[row];
    int tid = threadIdx.x;
    __shared__ float red[4];
    float v[3];
#pragma unroll
    for (int i = 0; i < 3; i++) {
        int c = tid + i * 256;
        v[i] = we[(size_t)tok * DD + c] + pe[(size_t)s * DD + c] + te[c];
    }
    float mean = bsum256(v[0] + v[1] + v[2], red) * (1.f / DD);
    float d0 = v[0] - mean, d1 = v[1] - mean, d2 = v[2] - mean;
    float var = bsum256(d0 * d0 + d1 * d1 + d2 * d2, red) * (1.f / DD);
    float inv = rsqrtf(var + 1e-12f);
    size_t base = (size_t)row * DD;
#pragma unroll
    for (int i = 0; i < 3; i++) {
        int c = tid + i * 256;
        float o = (v[i] - mean) * inv * g[c] + be[c];
        hf[base + c] = o;
        hb[base + c] = f2bf(o);
    }
}

// ---------------- residual add + LN (dual output) ----------------
__global__ __launch_bounds__(256) void add_ln(const float* __restrict__ res, const float* __restrict__ t,
                                              const float* __restrict__ g, const float* __restrict__ be,
                                              float* __restrict__ outf, unsigned short* __restrict__ outb) {
    int row = blockIdx.x;
    int tid = threadIdx.x;
    __shared__ float red[4];
    size_t base = (size_t)row * DD;
    float v[3];
#pragma unroll
    for (int i = 0; i < 3; i++) {
        int c = tid + i * 256;
        v[i] = res[base + c] + t[base + c];
    }
    float mean = bsum256(v[0] + v[1] + v[2], red) * (1.f / DD);
    float d0 = v[0] - mean, d1 = v[1] - mean, d2 = v[2] - mean;
    float var = bsum256(d0 * d0 + d1 * d1 + d2 * d2, red) * (1.f / DD);
    float inv = rsqrtf(var + 1e-12f);
#pragma unroll
    for (int i = 0; i < 3; i++) {
        int c = tid + i * 256;
        float o = (v[i] - mean) * inv * g[c] + be[c];
        outf[base + c] = o;
        outb[base + c] = f2bf(o);
    }
}

// ---------------- m97-style MFMA GEMM: 128x128 tile, BK=32, global_load_lds ----------------
// C[M,N] = A[M,K] * BT[N,K]^T + bias
// MODE 0: fp32 out; 1: bf16 out; 2: bf16 + exact GELU; 4: fused QKV epilogue
template <int MODE>
__global__ __launch_bounds__(256) void gemm128(const unsigned short* __restrict__ A,
                                               const unsigned short* __restrict__ BT,
                                               const float* __restrict__ bias, void* __restrict__ Cp,
                                               int M, int N, int K, int ldc,
                                               unsigned short* __restrict__ vt_out) {
    __shared__ __align__(16) unsigned short As[128 * 32];
    __shared__ __align__(16) unsigned short Bs[128 * 32];
    const int tid = threadIdx.x;
    const int lane = tid & 63, w = tid >> 6;
    const int fr = lane & 15, fg = lane >> 4;
    const int wr = w >> 1, wc = w & 1;
    const int m0 = blockIdx.y << 7, n0 = blockIdx.x << 7;
    const int srow = lane >> 2;          // 0..15
    const int skcol = (lane & 3) << 3;   // 0,8,16,24

    int arow0 = m0 + (w * 2 + 0) * 16 + srow;
    int arow1 = m0 + (w * 2 + 1) * 16 + srow;
    int brow0 = n0 + (w * 2 + 0) * 16 + srow;
    int brow1 = n0 + (w * 2 + 1) * 16 + srow;
    if (brow0 >= N) brow0 = N - 1;       // clamp (classifier tail); C-write guarded
    if (brow1 >= N) brow1 = N - 1;
    const unsigned short* aptr0 = A + (size_t)arow0 * K + skcol;
    const unsigned short* aptr1 = A + (size_t)arow1 * K + skcol;
    const unsigned short* bptr0 = BT + (size_t)brow0 * K + skcol;
    const unsigned short* bptr1 = BT + (size_t)brow1 * K + skcol;
    unsigned short* lA0 = &As[(w * 2 + 0) * 512];
    unsigned short* lA1 = &As[(w * 2 + 1) * 512];
    unsigned short* lB0 = &Bs[(w * 2 + 0) * 512];
    unsigned short* lB1 = &Bs[(w * 2 + 1) * 512];

    f32x4 acc[4][4] = {};
    for (int k0 = 0; k0 < K; k0 += 32) {
        __syncthreads();
        GLOAD16(aptr0 + k0, lA0);
        GLOAD16(aptr1 + k0, lA1);
        GLOAD16(bptr0 + k0, lB0);
        GLOAD16(bptr1 + k0, lB1);
        __syncthreads();
        bh8 a[4], b[4];
#pragma unroll
        for (int mi = 0; mi < 4; mi++) a[mi] = *(const bh8*)&As[(wr * 64 + mi * 16 + fr) * 32 + fg * 8];
#pragma unroll
        for (int ni = 0; ni < 4; ni++) b[ni] = *(const bh8*)&Bs[(wc * 64 + ni * 16 + fr) * 32 + fg * 8];
        __builtin_amdgcn_s_setprio(1);
#pragma unroll
        for (int mi = 0; mi < 4; mi++)
#pragma unroll
            for (int ni = 0; ni < 4; ni++)
                acc[mi][ni] = __builtin_amdgcn_mfma_f32_16x16x32_bf16(a[mi], b[ni], acc[mi][ni], 0, 0, 0);
        __builtin_amdgcn_s_setprio(0);
    }

    float* Cf = (float*)Cp;
    unsigned short* Cb = (unsigned short*)Cp;
#pragma unroll
    for (int mi = 0; mi < 4; mi++) {
#pragma unroll
        for (int ni = 0; ni < 4; ni++) {
            int col = n0 + wc * 64 + ni * 16 + fr;
            int rbase = m0 + wr * 64 + mi * 16 + fg * 4;
            if (MODE == 4) {
                float bb = bias[col];
                if (col < 2 * DD) {
#pragma unroll
                    for (int r = 0; r < 4; r++)
                        Cb[(size_t)(rbase + r) * (2 * DD) + col] = f2bf(acc[mi][ni][r] + bb);
                } else {
                    int g = col - 2 * DD, h = g >> 6, d = g & 63;
                    int bi = rbase >> 10, s0 = rbase & 1023;
                    us4 val;
#pragma unroll
                    for (int r = 0; r < 4; r++) val[r] = f2bf(acc[mi][ni][r] + bb);
                    *(us4*)&vt_out[(((size_t)bi * HH + h) * DH + d) * SS + s0] = val;
                }
            } else if (col < N) {
                float bb = bias[col];
#pragma unroll
                for (int r = 0; r < 4; r++) {
                    float v = acc[mi][ni][r] + bb;
                    if (MODE == 2) v = 0.5f * v * (1.0f + erff(v * 0.70710678118f));
                    if (MODE == 0) Cf[(size_t)(rbase + r) * ldc + col] = v;
                    else Cb[(size_t)(rbase + r) * ldc + col] = f2bf(v);
                }
            }
        }
    }
}

// ---------------- flash attention, double-buffered prefetch ----------------
// grid (S/64, H, B), 4 waves, 16 Q-rows/wave; qt descending for tail packing.
// LDS layout: k-half-split [kk][64][32] (m97 bank profile); Ps XOR-swizzled per wave.
__global__ __launch_bounds__(256) void flash_attn(const unsigned short* __restrict__ qkbuf,
                                                  const unsigned short* __restrict__ VT,
                                                  unsigned short* __restrict__ ctxb) {
    const int qt = (int)gridDim.x - 1 - blockIdx.x;
    const int h = blockIdx.y, b = blockIdx.z;
    const int tid = threadIdx.x;
    const int lane = tid & 63, w = tid >> 6;
    const int fr = lane & 15, fg = lane >> 4;
    __shared__ __align__(16) unsigned short Qs[2][64][32];       // [kk][row][d-half]
    __shared__ __align__(16) unsigned short Ks[2][2][64][32];    // [buf][kk][row][d-half]
    __shared__ __align__(16) unsigned short Vt[2][2][64][32];    // [buf][kkey][d][key-half]
    __shared__ __align__(16) unsigned short Ps[4][2][16][32];    // [wave][kk][q][key-half^swz]

    const int srow = lane >> 2, scol = (lane & 3) << 3;
    const size_t qkrow0 = (size_t)(b * SS) * (2 * DD);

    // Q stage (2 insts/wave)
#pragma unroll
    for (int j = 0; j < 2; j++) {
        int gg = w * 2 + j, kk = gg >> 2, rg = gg & 3;
        const unsigned short* src = qkbuf + qkrow0 + (size_t)(qt * 64 + rg * 16 + srow) * (2 * DD)
                                    + h * 64 + kk * 32 + scol;
        GLOAD16(src, &Qs[kk][rg * 16][0]);
    }

    // K/V stage (4 insts/wave per tile)
    auto stageKV = [&](int bf, int kt) {
#pragma unroll
        for (int j = 0; j < 2; j++) {
            int gg = w * 2 + j, kk = gg >> 2, rg = gg & 3;
            const unsigned short* ks = qkbuf + qkrow0 + (size_t)(kt * 64 + rg * 16 + srow) * (2 * DD)
                                       + DD + h * 64 + kk * 32 + scol;
            GLOAD16(ks, &Ks[bf][kk][rg * 16][0]);
            const unsigned short* vs = VT + (((size_t)b * HH + h) * DH + rg * 16 + srow) * SS
                                       + kt * 64 + kk * 32 + scol;
            GLOAD16(vs, &Vt[bf][kk][rg * 16][0]);
        }
    };

    stageKV(0, 0);

    f32x4 o[4] = {};
    float m[4], l[4];
#pragma unroll
    for (int r = 0; r < 4; r++) { m[r] = -3e30f; l[r] = 0.f; }

    const int nkt = (qt == 0) ? 1 : qt + 1;
    __syncthreads();   // drain Q + tile0 (compiler emits vmcnt(0) before barrier)
    int cur = 0;
    const int pxor = ((fr >> 2) & 3) << 3;

    for (int kt = 0; kt < nkt; kt++) {
        if (kt + 1 < nkt) stageKV(cur ^ 1, kt + 1);   // prefetch; drains at bottom barrier

        // QK^T
        f32x4 s[4] = {};
        bh8 a0 = *(const bh8*)&Qs[0][w * 16 + fr][fg * 8];
        bh8 a1 = *(const bh8*)&Qs[1][w * 16 + fr][fg * 8];
        __builtin_amdgcn_s_setprio(1);
#pragma unroll
        for (int cf = 0; cf < 4; cf++) {
            bh8 b0 = *(const bh8*)&Ks[cur][0][cf * 16 + fr][fg * 8];
            bh8 b1 = *(const bh8*)&Ks[cur][1][cf * 16 + fr][fg * 8];
            s[cf] = __builtin_amdgcn_mfma_f32_16x16x32_bf16(a0, b0, s[cf], 0, 0, 0);
            s[cf] = __builtin_amdgcn_mfma_f32_16x16x32_bf16(a1, b1, s[cf], 0, 0, 0);
        }
        __builtin_amdgcn_s_setprio(0);

        const bool diag = (qt > 0) && (kt == qt);
#pragma unroll
        for (int cf = 0; cf < 4; cf++) {
#pragma unroll
            for (int r = 0; r < 4; r++) {
                float v = s[cf][r] * 0.125f;
                if (diag) {
                    int key = cf * 16 + fr;
                    int qrow = w * 16 + fg * 4 + r;
                    if (key > qrow) v = -1e30f;
                }
                s[cf][r] = v;
            }
        }
        // online softmax (per-row stats across 16-lane group)
        float sc[4], mn[4];
#pragma unroll
        for (int r = 0; r < 4; r++) {
            float v = fmaxf(fmaxf(s[0][r], s[1][r]), fmaxf(s[2][r], s[3][r]));
#pragma unroll
            for (int off = 1; off < 16; off <<= 1) v = fmaxf(v, __shfl_xor(v, off));
            mn[r] = fmaxf(m[r], v);
            sc[r] = __expf(m[r] - mn[r]);
            m[r] = mn[r];
        }
#pragma unroll
        for (int cf = 0; cf < 4; cf++) {
#pragma unroll
            for (int r = 0; r < 4; r++) s[cf][r] = __expf(s[cf][r] - mn[r]);
        }
#pragma unroll
        for (int r = 0; r < 4; r++) {
            float v = s[0][r] + s[1][r] + s[2][r] + s[3][r];
#pragma unroll
            for (int off = 1; off < 16; off <<= 1) v += __shfl_xor(v, off);
            l[r] = l[r] * sc[r] + v;
        }
#pragma unroll
        for (int df = 0; df < 4; df++) {
#pragma unroll
            for (int r = 0; r < 4; r++) o[df][r] *= sc[r];
        }
        // P -> per-wave LDS (swizzled transpose), element (q=fg*4+r, col=cf*16+fr)
#pragma unroll
        for (int cf = 0; cf < 4; cf++) {
#pragma unroll
            for (int r = 0; r < 4; r++)
                Ps[w][cf >> 1][fg * 4 + r][(((cf & 1) << 4) + fr) ^ (fg << 3)] = f2bf(s[cf][r]);
        }
        bh8 pa0 = *(const bh8*)&Ps[w][0][fr][(fg * 8) ^ pxor];
        bh8 pa1 = *(const bh8*)&Ps[w][1][fr][(fg * 8) ^ pxor];
        __builtin_amdgcn_s_setprio(1);
#pragma unroll
        for (int df = 0; df < 4; df++) {
            bh8 vb0 = *(const bh8*)&Vt[cur][0][df * 16 + fr][fg * 8];
            bh8 vb1 = *(const bh8*)&Vt[cur][1][df * 16 + fr][fg * 8];
            o[df] = __builtin_amdgcn_mfma_f32_16x16x32_bf16(pa0, vb0, o[df], 0, 0, 0);
            o[df] = __builtin_amdgcn_mfma_f32_16x16x32_bf16(pa1, vb1, o[df], 0, 0, 0);
        }
        __builtin_amdgcn_s_setprio(0);
        __syncthreads();   // prefetch drained + buffers protected
        cur ^= 1;
    }
#pragma unroll
    for (int df = 0; df < 4; df++) {
#pragma unroll
        for (int r = 0; r < 4; r++) {
            int q = qt * 64 + w * 16 + fg * 4 + r;
            float v = o[df][r] / l[r];
            ctxb[(((size_t)b * SS + q) * HH + h) * DH + df * 16 + fr] = f2bf(v);
        }
    }
}

// ---------------- gather classifier rows (s in [64,1024)) into compact [7680,768] bf16 ----------------
__global__ void gather_rows(const unsigned short* __restrict__ hb, unsigned short* __restrict__ hc) {
    int idx = blockIdx.x * 256 + threadIdx.x;
    if (idx >= NROWS * (DD / 8)) return;
    int g = idx / (DD / 8), c8 = (idx % (DD / 8)) * 8;
    int b = g / CLEN, cc = g % CLEN;
    *(bh8*)&hc[(size_t)g * DD + c8] = *(const bh8*)&hb[((size_t)(b * SS + 64 + cc)) * DD + c8];
}

// ---------------- classifier logsumexp state ----------------
__global__ void init_state(float* stM, float* stS, float* stT) {
    int i = blockIdx.x * 256 + threadIdx.x;
    if (i < NROWS) { stM[i] = -3e38f; stS[i] = 0.f; stT[i] = 0.f; }
}

__global__ __launch_bounds__(256) void lse_merge(const unsigned short* __restrict__ lchunk,
                                                 const int* __restrict__ y,
                                                 float* __restrict__ stM, float* __restrict__ stS,
                                                 float* __restrict__ stT, int c0, int cn) {
    int row = blockIdx.x, tid = threadIdx.x;
    int yv = y[row];
    int tloc = yv - c0;
    const unsigned short* lr = lchunk + (size_t)row * cn;
    float mx = -3e38f, sm = 0.f, tl = 0.f;
    for (int c = tid * 8; c < cn; c += 2048) {
        bh8 lv = *(const bh8*)&lr[c];
#pragma unroll
        for (int u = 0; u < 8; u++) {
            float d = bf2f((unsigned short)lv[u]);
            float m2 = fmaxf(mx, d);
            sm = sm * __expf(mx - m2) + __expf(d - m2);
            mx = m2;
            if (c + u == tloc) tl = d;
        }
    }
    __shared__ float red[4];
    float m = mx;
#pragma unroll
    for (int o = 32; o; o >>= 1) m = fmaxf(m, __shfl_down(m, o));
    if ((tid & 63) == 0) red[tid >> 6] = m;
    __syncthreads();
    float gmax = fmaxf(fmaxf(red[0], red[1]), fmaxf(red[2], red[3]));
    __syncthreads();
    float s = sm * __expf(mx - gmax);
#pragma unroll
    for (int o = 32; o; o >>= 1) s += __shfl_down(s, o);
    if ((tid & 63) == 0) red[tid >> 6] = s;
    __syncthreads();
    float gsum = red[0] + red[1] + red[2] + red[3];
    __syncthreads();
    float t = tl;
#pragma unroll
    for (int o = 32; o; o >>= 1) t += __shfl_down(t, o);
    if ((tid & 63) == 0) red[tid >> 6] = t;
    __syncthreads();
    float gt = red[0] + red[1] + red[2] + red[3];
    if (tid == 0) {
        float M0 = stM[row], S0 = stS[row];
        float M = fmaxf(M0, gmax);
        float S = S0 * __expf(M0 - M) + gsum * __expf(gmax - M);
        stM[row] = M;
        stS[row] = S;
        if (tloc >= 0 && tloc < cn) stT[row] = gt;
    }
}

__global__ __launch_bounds__(256) void final_reduce(const float* __restrict__ stM, const float* __restrict__ stS,
                                                    const float* __restrict__ stT, const int* __restrict__ y,
                                                    float* __restrict__ out) {
    int tid = threadIdx.x;
    float s = 0.f, c = 0.f;
    for (int i = tid; i < NROWS; i += 256) {
        if (y[i] != -100) {
            s += stM[i] + logf(stS[i]) - stT[i];
            c += 1.f;
        }
    }
    __shared__ float red[4];
    float gs = bsum256(s, red);
    float gc = bsum256(c, red);
    if (tid == 0) out[0] = gs / fmaxf(gc, 1.f);
}

// ---------------- launcher ----------------
extern "C" void kernel_launch(void* const* d_in, const int* in_sizes, int n_in,
                              void* d_out, int out_size, void* d_ws, size_t ws_size,
                              hipStream_t stream) {
    const int* x = (const int*)d_in[0];
    const int* y = (const int*)d_in[1];
    const float* we = (const float*)d_in[2];
    const float* pe = (const float*)d_in[3];
    const float* te = (const float*)d_in[4];
    const float* eg = (const float*)d_in[5];
    const float* eb = (const float*)d_in[6];
    const float* Wq = (const float*)d_in[7];
    const float* bq = (const float*)d_in[8];
    const float* Wk = (const float*)d_in[9];
    const float* bk = (const float*)d_in[10];
    const float* Wv = (const float*)d_in[11];
    const float* bv = (const float*)d_in[12];
    const float* Wo = (const float*)d_in[13];
    const float* bo = (const float*)d_in[14];
    const float* g1 = (const float*)d_in[15];
    const float* b1n = (const float*)d_in[16];
    const float* W1 = (const float*)d_in[17];
    const float* b1 = (const float*)d_in[18];
    const float* W2 = (const float*)d_in[19];
    const float* b2 = (const float*)d_in[20];
    const float* g2 = (const float*)d_in[21];
    const float* b2n = (const float*)d_in[22];
    const float* clsW = (const float*)d_in[23];
    const float* clsb = (const float*)d_in[24];
    float* out = (float*)d_out;

    char* ws = (char*)d_ws;
    size_t off = 0;
    auto alloc = [&](size_t n) {
        void* p = ws + off;
        off += n;
        off = (off + 255) & ~(size_t)255;
        return p;
    };
    float* h   = (float*)alloc((size_t)TOKS * DD * 4);
    float* h1  = (float*)alloc((size_t)TOKS * DD * 4);
    float* tmp = (float*)alloc((size_t)TOKS * DD * 4);
    unsigned short* hb   = (unsigned short*)alloc((size_t)TOKS * DD * 2);
    unsigned short* h1b  = (unsigned short*)alloc((size_t)TOKS * DD * 2);
    unsigned short* qkbuf = (unsigned short*)alloc((size_t)TOKS * 2 * DD * 2);
    unsigned short* vtb  = (unsigned short*)alloc((size_t)TOKS * DD * 2);
    unsigned short* ctxb = (unsigned short*)alloc((size_t)TOKS * DD * 2);
    unsigned short* ffnb = (unsigned short*)alloc((size_t)TOKS * FF * 2);
    unsigned short* wqkvT = (unsigned short*)alloc((size_t)NQKV * DD * 2);
    unsigned short* woT = (unsigned short*)alloc((size_t)DD * DD * 2);
    unsigned short* w1T = (unsigned short*)alloc((size_t)DD * FF * 2);
    unsigned short* w2T = (unsigned short*)alloc((size_t)DD * FF * 2);
    unsigned short* clsT = (unsigned short*)alloc((size_t)VV * DD * 2);
    unsigned short* hc = (unsigned short*)alloc((size_t)NROWS * DD * 2);
    unsigned short* lchunk = (unsigned short*)alloc((size_t)NROWS * CHUNK * 2);
    float* bqkv = (float*)alloc((size_t)LL * NQKV * 4);
    float* stM = (float*)alloc(NROWS * 4);
    float* stS = (float*)alloc(NROWS * 4);
    float* stT = (float*)alloc(NROWS * 4);

    dim3 tb(32, 8);
    transpose_f32_bf16<<<dim3((VV + 31) / 32, DD / 32), tb, 0, stream>>>(clsW, clsT, DD, VV);
    concat_bias_all<<<(LL * NQKV + 255) / 256, 256, 0, stream>>>(bq, bk, bv, bqkv);
    embed_ln<<<TOKS, 256, 0, stream>>>(x, we, pe, te, eg, eb, h, hb);

    for (int l = 0; l < LL; l++) {
        transpose_layer<<<6912, tb, 0, stream>>>(Wq + (size_t)l * DD * DD, Wk + (size_t)l * DD * DD,
                                                 Wv + (size_t)l * DD * DD, Wo + (size_t)l * DD * DD,
                                                 W1 + (size_t)l * DD * FF, W2 + (size_t)l * FF * DD,
                                                 wqkvT, woT, w1T, w2T);

        gemm128<4><<<dim3(NQKV / 128, TOKS / 128), 256, 0, stream>>>(hb, wqkvT, bqkv + (size_t)l * NQKV,
                                                                     qkbuf, TOKS, NQKV, DD, NQKV, vtb);

        flash_attn<<<dim3(SS / 64, HH, BB), 256, 0, stream>>>(qkbuf, vtb, ctxb);

        gemm128<0><<<dim3(DD / 128, TOKS / 128), 256, 0, stream>>>(ctxb, woT, bo + (size_t)l * DD, tmp,
                                                                   TOKS, DD, DD, DD, nullptr);
        add_ln<<<TOKS, 256, 0, stream>>>(h, tmp, g1 + (size_t)l * DD, b1n + (size_t)l * DD, h1, h1b);

        gemm128<2><<<dim3(FF / 128, TOKS / 128), 256, 0, stream>>>(h1b, w1T, b1 + (size_t)l * FF, ffnb,
                                                                   TOKS, FF, DD, FF, nullptr);
        gemm128<0><<<dim3(DD / 128, TOKS / 128), 256, 0, stream>>>(ffnb, w2T, b2 + (size_t)l * DD, tmp,
                                                                   TOKS, DD, FF, DD, nullptr);
        add_ln<<<TOKS, 256, 0, stream>>>(h1, tmp, g2 + (size_t)l * DD, b2n + (size_t)l * DD, h, hb);
    }

    gather_rows<<<(NROWS * (DD / 8) + 255) / 256, 256, 0, stream>>>(hb, hc);
    init_state<<<(NROWS + 255) / 256, 256, 0, stream>>>(stM, stS, stT);
    for (int c0 = 0; c0 < VV; c0 += CHUNK) {
        int cn = VV - c0 < CHUNK ? VV - c0 : CHUNK;
        gemm128<1><<<dim3((cn + 127) / 128, NROWS / 128), 256, 0, stream>>>(hc, clsT + (size_t)c0 * DD,
                                                                            clsb + c0, lchunk,
                                                                            NROWS, cn, DD, cn, nullptr);
        lse_merge<<<NROWS, 256, 0, stream>>>(lchunk, y, stM, stS, stT, c0, cn);
    }
    final_reduce<<<1, 256, 0, stream>>>(stM, stS, stT, y, out);
}